// Round 8
// baseline (12857.663 us; speedup 1.0000x reference)
//
#include <hip/hip_runtime.h>
#include <math.h>

#define S_LEN 1024
#define BATCH 2048
#define MTILE 16              // 16 batches/block: two independent 8-batch groups
#define HID   128
#define NBLK  (BATCH / MTILE)   // 128 blocks, 1024 threads (16 waves) each
#define INV2048 (1.0f / 2048.0f)
#define NLOG2E (-1.44269504088896341f)   // folded into M/A gate weights

// ws layout, offsets in _Float16 elements. Ten [128][128] hi/lo weight
// arrays; M/A-gate weights are pre-scaled by -log2(e) so the sigmoid is
// rcp(1 + exp2(pre)) with a bare v_exp_f32.
#define H_M1H 0
#define H_M1L 16384
#define H_MSH 32768
#define H_MSL 49152
#define H_ASH 65536
#define H_ASL 81920
#define H_WMH 98304      // [128][128] WtauM[:,128:256] hi (scaled)
#define H_WML 114688
#define H_WBH 131072     // [128][128] WtauAdp[:,128:256] hi (scaled)
#define H_WBL 147456
// f32 ext-coefficient table: 9 arrays of [128] floats, gate-major:
// idx (gate*3 + col)*128 + h ; gate 0=d,1=M,2=A ; col 0=bias,1=x0,2=x1.
// M/A rows pre-scaled by -log2(e); d row unscaled.
#define F_EXT      81920     // float index (== 163840 halfs)
#define OFF_PART_F 83072     // float index of per-block partials [128]

typedef _Float16 half8 __attribute__((ext_vector_type(8)));
typedef _Float16 half4 __attribute__((ext_vector_type(4)));
typedef _Float16 half2h __attribute__((ext_vector_type(2)));
typedef float floatx4 __attribute__((ext_vector_type(4)));
typedef float floatx2 __attribute__((ext_vector_type(2)));

#define MFMA(a, b, c) __builtin_amdgcn_mfma_f32_16x16x32_f16((a), (b), (c), 0, 0, 0)

__device__ __forceinline__ void put_hl(_Float16* ws, int hiBase, int loBase,
                                       int idx, float v) {
  _Float16 hi = (_Float16)v;
  ws[hiBase + idx] = hi;
  ws[loBase + idx] = (_Float16)((v - (float)hi) * 2048.0f);
}

// DPP row_ror:8 == xor-8 within each 16-lane row (8 = half the 16-ring).
// VALU pipe instead of the over-subscribed LDS pipe.
__device__ __forceinline__ float dpp_xor8(float v) {
  int sw = __builtin_amdgcn_update_dpp(0, __float_as_int(v),
                                       0x128 /*row_ror:8*/, 0xF, 0xF, true);
  return __int_as_float(sw);
}

// u-scheme fold for gates with a cross term (M, A): pre-combine
// u_r = hi_r + lo_r/2048 on the natural side, then one exchange each way.
// Lane c finishes r=0,1; lane c+8 finishes r=2,3.
__device__ __forceinline__ void fold_u(floatx4 g1, floatx4 g2, bool side,
                                       float out[2]) {
  float u0 = g1[0] + g2[0] * INV2048;
  float u1 = g1[1] + g2[1] * INV2048;
  float u2 = g1[2] + g2[2] * INV2048;
  float u3 = g1[3] + g2[3] * INV2048;
  float t0 = dpp_xor8(g1[0]);   // act receives cross_0
  float t1 = dpp_xor8(g1[1]);
  float t2 = dpp_xor8(u2);      // side receives act's u2
  float t3 = dpp_xor8(u3);
  float base0 = side ? t2 : u0, add0 = side ? g1[2] : t0;
  float base1 = side ? t3 : u1, add1 = side ? g1[3] : t1;
  out[0] = base0 + add0 * INV2048;
  out[1] = base1 + add1 * INV2048;
}

// d gate: spk cols 8-15 are exactly 0 -> cross terms vanish on both sides.
__device__ __forceinline__ void fold_d(floatx4 g1, floatx4 g2, bool side,
                                       float out[2]) {
  float u0 = g1[0] + g2[0] * INV2048;
  float u1 = g1[1] + g2[1] * INV2048;
  float u2 = g1[2] + g2[2] * INV2048;
  float u3 = g1[3] + g2[3] * INV2048;
  float t2 = dpp_xor8(u2);
  float t3 = dpp_xor8(u3);
  out[0] = side ? t2 : u0;
  out[1] = side ? t3 : u1;
}

// ---- prep: fold dense->tau coupling into f16 hi/lo fragment arrays, plus
// the f32 ext-coefficient table. M/A-gate paths pre-scaled by -log2(e).
__global__ __launch_bounds__(192) void prep(
    const float* __restrict__ W1x, const float* __restrict__ b1x,
    const float* __restrict__ WtauM, const float* __restrict__ btauM,
    const float* __restrict__ WtauAdp, const float* __restrict__ btauAdp,
    _Float16* __restrict__ ws) {
  const int h = blockIdx.x, k = threadIdx.x;
  if (k >= 131) return;
  if (k < 128) {
    float w1 = W1x[h * 130 + 2 + k];
    float s1 = 0.f, s2 = 0.f;
    for (int d = 0; d < 128; ++d) {
      float wd = W1x[d * 130 + 2 + k];
      s1 += WtauM[h * 256 + d] * wd;
      s2 += WtauAdp[h * 256 + d] * wd;
    }
    put_hl(ws, H_M1H, H_M1L, h * 128 + k, w1);
    put_hl(ws, H_MSH, H_MSL, h * 128 + k, s1 * NLOG2E);
    put_hl(ws, H_ASH, H_ASL, h * 128 + k, s2 * NLOG2E);
    put_hl(ws, H_WMH, H_WML, h * 128 + k, WtauM[h * 256 + 128 + k] * NLOG2E);
    put_hl(ws, H_WBH, H_WBL, h * 128 + k, WtauAdp[h * 256 + 128 + k] * NLOG2E);
  } else {
    const int col = k - 128;   // 0: bias, 1: x0-coef, 2: x1-coef
    float m1v = (col == 0) ? b1x[h] : W1x[h * 130 + (col - 1)];
    float sm = 0.f, sa = 0.f;
    for (int d = 0; d < 128; ++d) {
      float cv = (col == 0) ? b1x[d] : W1x[d * 130 + (col - 1)];
      sm += WtauM[h * 256 + d] * cv;
      sa += WtauAdp[h * 256 + d] * cv;
    }
    if (col == 0) { sm += btauM[h]; sa += btauAdp[h]; }
    float* EXTF = (float*)ws + F_EXT;
    EXTF[(0 * 3 + col) * 128 + h] = m1v;
    EXTF[(1 * 3 + col) * 128 + h] = sm * NLOG2E;
    EXTF[(2 * 3 + col) * 128 + h] = sa * NLOG2E;
  }
}

// State slabs, PER GROUP [2]: mem/bbp per k-chunk 1 KB, half-index
// (q'*16+n')*8+j holds B[k=f*32+q'*8+j][n']; n'=0..7 hi, n'=8..15 lo(x2048).
// spk packed to the 8 real cols (512 B/chunk, no lo). Side lanes
// broadcast-read zero16 for S. Two groups = two independent recurrences
// sharing the block barrier only.
struct SLds {
  _Float16 spk[2][2][4][256];   // [grp][buf][f][..]
  _Float16 zero16[8];           // 16 B of zeros, same-address broadcast read
  _Float16 mem[2][2][4][512];
  _Float16 bbp[2][2][4][512];
  float red[2][8][8];           // [grp][wg][batch]
  float red2[16];
};

__global__ __launch_bounds__(1024, 4) void snn_main(
    const float* __restrict__ x, const float* __restrict__ y,
    const float* __restrict__ h0m, const float* __restrict__ h0s,
    const float* __restrict__ h0b,
    const float* __restrict__ Wlin, const float* __restrict__ blin,
    const _Float16* __restrict__ W, float* __restrict__ wsout) {
  __shared__ SLds L;

  const int tid  = threadIdx.x;
  const int w    = tid >> 6;      // wave 0..15
  const int grp  = w >> 3;        // batch group 0/1 (independent recurrence)
  const int wg   = w & 7;         // wave-within-group, owns h-slice [16wg,..)
  const int lane = tid & 63;
  const int c    = lane & 15;     // A-frag m / B-frag n / C col
  const int q    = lane >> 4;
  const int cc   = c & 7;         // batch column within the group tile
  const int bbase = blockIdx.x * MTILE;
  const int bg   = bbase + grp * 8;   // this group's batch base
  const bool act  = (c < 8);
  const bool side = !act;         // side lanes own neurons r=2,3

  // ---- Register-resident A-frag weights (MFMA-only -> AGPR side)
  half8 m1h[4], m1l[4], msh[4], msl[4], ash[4], asl[4];
  half8 wmh[4], wml[4], wbh[4], wbl[4];
  {
    const int hA = wg * 16 + c;
#pragma unroll
    for (int f = 0; f < 4; ++f) {
      const int o = hA * 128 + f * 32 + q * 8;
      m1h[f] = *(const half8*)&W[H_M1H + o];
      m1l[f] = *(const half8*)&W[H_M1L + o];
      msh[f] = *(const half8*)&W[H_MSH + o];
      msl[f] = *(const half8*)&W[H_MSL + o];
      ash[f] = *(const half8*)&W[H_ASH + o];
      asl[f] = *(const half8*)&W[H_ASL + o];
      wmh[f] = *(const half8*)&W[H_WMH + o];
      wml[f] = *(const half8*)&W[H_WML + o];
      wbh[f] = *(const half8*)&W[H_WBH + o];
      wbl[f] = *(const half8*)&W[H_WBL + o];
    }
  }

  if (tid == 0) {   // 16 B zero block for c>=8 broadcast S reads
    *(half8*)&L.zero16[0] = half8{0, 0, 0, 0, 0, 0, 0, 0};
  }

  // ---- f32 ext coefficients for this lane's 2 neurons (h0i, h0i+1)
  const int h0i = wg * 16 + q * 4 + (side ? 2 : 0);
  const float* CF = (const float*)W + F_EXT;
  floatx2 cd0 = *(const floatx2*)&CF[0 * 128 + h0i];
  floatx2 cd1 = *(const floatx2*)&CF[1 * 128 + h0i];
  floatx2 cd2 = *(const floatx2*)&CF[2 * 128 + h0i];
  floatx2 cm0 = *(const floatx2*)&CF[3 * 128 + h0i];
  floatx2 cm1 = *(const floatx2*)&CF[4 * 128 + h0i];
  floatx2 cm2 = *(const floatx2*)&CF[5 * 128 + h0i];
  floatx2 ca0 = *(const floatx2*)&CF[6 * 128 + h0i];
  floatx2 ca1 = *(const floatx2*)&CF[7 * 128 + h0i];
  floatx2 ca2 = *(const floatx2*)&CF[8 * 128 + h0i];

  // ---- Per-lane recurrent state: EVERY lane owns 2 neurons.
  float memv[2], spk[2], bb[2];
  {
    const int gi = (bg + cc) * HID + h0i;
    float2 tm = *(const float2*)&h0m[gi];
    float2 ts = *(const float2*)&h0s[gi];
    float2 tb = *(const float2*)&h0b[gi];
    memv[0] = tm.x; memv[1] = tm.y;
    spk[0]  = ts.x; spk[1]  = ts.y;
    bb[0]   = tb.x; bb[1]   = tb.y;
  }

  // State value (h = wg*16+q*4+side*2+rr) enters GEMM2 as B[k=h][n]:
  // chunk fW = wg>>1, granule qp = (wg&1)*2 + (q>>1), j = (q&1)*4+side*2+rr.
  const int fW  = wg >> 1;
  const int qp  = (wg & 1) * 2 + (q >> 1);
  const int jo  = (q & 1) * 4 + (side ? 2 : 0);
  const int wiH = (qp * 16 + cc) * 8 + jo;        // mem/bbp hi (n'=cc)
  const int wiL = wiH + 64;                       // mem/bbp lo (n'=cc+8)
  const int wiS = (qp * 8 + cc) * 8 + jo;         // packed spk
  const int ri  = lane * 8;                       // mem/bbp read (identity)
  const _Float16* spkB0 = act ? &L.spk[grp][0][0][(q * 8 + cc) * 8] : L.zero16;
  const _Float16* spkB1 = act ? &L.spk[grp][1][0][(q * 8 + cc) * 8] : L.zero16;
  const int spkStep = act ? 256 : 0;

  {   // initial state into buf 0 (all lanes, 2 values each)
    half2h ps2, mh2, ml2, bh2, bl2;
#pragma unroll
    for (int rr = 0; rr < 2; ++rr) {
      ps2[rr] = (_Float16)spk[rr];
      float v = memv[rr]; _Float16 hi = (_Float16)v;
      mh2[rr] = hi; ml2[rr] = (_Float16)((v - (float)hi) * 2048.0f);
      v = bb[rr]; hi = (_Float16)v;
      bh2[rr] = hi; bl2[rr] = (_Float16)((v - (float)hi) * 2048.0f);
    }
    *(half2h*)&L.spk[grp][0][fW][wiS] = ps2;
    *(half2h*)&L.mem[grp][0][fW][wiH] = mh2;
    *(half2h*)&L.mem[grp][0][fW][wiL] = ml2;
    *(half2h*)&L.bbp[grp][0][fW][wiH] = bh2;
    *(half2h*)&L.bbp[grp][0][fW][wiL] = bl2;
  }
  __syncthreads();

  // Per-lane x stream for batch bg+cc, prefetched one step ahead.
  const float* xb = x + (size_t)(bg + cc) * 2;
  float2 xv = *(const float2*)xb;   // x at t=0

#pragma unroll 1
  for (int t = 0; t < S_LEN; ++t) {
    const int p = t & 1, pn = p ^ 1;
    const size_t tn = (t + 1 < S_LEN) ? (size_t)(t + 1) : (size_t)t;
    float2 xnx = *(const float2*)(xb + tn * (size_t)(BATCH * 2));  // prefetch

    const _Float16* sB = p ? spkB1 : spkB0;

    floatx4 d1 = {0.f,0.f,0.f,0.f}, d2 = {0.f,0.f,0.f,0.f};
    floatx4 m1 = {0.f,0.f,0.f,0.f}, m2 = {0.f,0.f,0.f,0.f};
    floatx4 a1 = {0.f,0.f,0.f,0.f}, a2 = {0.f,0.f,0.f,0.f};

#pragma unroll
    for (int f = 0; f < 4; ++f) {
      half8 S = *(const half8*)&sB[f * spkStep];        // [spk] (0 for c>=8)
      half8 M = *(const half8*)&L.mem[grp][p][f][ri];   // [mh  | ml]
      half8 B = *(const half8*)&L.bbp[grp][p][f][ri];   // [bh  | bl]
      d1 = MFMA(m1h[f], S, d1);
      d2 = MFMA(m1l[f], S, d2);
      m1 = MFMA(msh[f], S, m1);
      m1 = MFMA(wmh[f], M, m1);    // cols0-7: wmh*mh ; cols8-15: wmh*ml
      m2 = MFMA(msl[f], S, m2);
      m2 = MFMA(wml[f], M, m2);    // cols0-7: wml*mh ; cols8-15: junk
      a1 = MFMA(ash[f], S, a1);
      a1 = MFMA(wbh[f], B, a1);
      a2 = MFMA(asl[f], S, a2);
      a2 = MFMA(wbl[f], B, a2);
    }

    const float xc0 = xv.x, xc1 = xv.y;

    // M gate first: its exp2 issues while the a/d folds run on the VALU.
    float preM[2], preA[2], den[2];
    fold_u(m1, m2, side, preM);
    float pM0 = preM[0] + cm0[0] + cm1[0] * xc0 + cm2[0] * xc1;
    float pM1 = preM[1] + cm0[1] + cm1[1] * xc0 + cm2[1] * xc1;
    float eM0 = __builtin_amdgcn_exp2f(pM0);   // weights pre-scaled by -log2e
    float eM1 = __builtin_amdgcn_exp2f(pM1);
    fold_u(a1, a2, side, preA);
    float pA0 = preA[0] + ca0[0] + ca1[0] * xc0 + ca2[0] * xc1;
    float pA1 = preA[1] + ca0[1] + ca1[1] * xc0 + ca2[1] * xc1;
    float eA0 = __builtin_amdgcn_exp2f(pA0);
    float eA1 = __builtin_amdgcn_exp2f(pA1);
    fold_d(d1, d2, side, den);

    float tM[2] = { __builtin_amdgcn_rcpf(1.0f + eM0),
                    __builtin_amdgcn_rcpf(1.0f + eM1) };
    float tA[2] = { __builtin_amdgcn_rcpf(1.0f + eA0),
                    __builtin_amdgcn_rcpf(1.0f + eA1) };

    // ---- Elementwise update: 2 real neurons per lane (64 lanes busy).
    half2h ps2, mh2, ml2, bh2, bl2;
#pragma unroll
    for (int rr = 0; rr < 2; ++rr) {
      float dv = den[rr] + cd0[rr] + cd1[rr] * xc0 + cd2[rr] * xc1;
      bb[rr] = tA[rr] * bb[rr] + (1.0f - tA[rr]) * spk[rr];
      float Bth = 0.01f + 1.8f * bb[rr];
      memv[rr] = memv[rr] * tM[rr] + (1.0f - tM[rr]) * dv - Bth * spk[rr];
      spk[rr] = (memv[rr] - Bth) > 0.0f ? 1.0f : 0.0f;
      ps2[rr] = (_Float16)spk[rr];
      float v = bb[rr]; _Float16 hi = (_Float16)v;
      bh2[rr] = hi; bl2[rr] = (_Float16)((v - (float)hi) * 2048.0f);
      v = memv[rr]; hi = (_Float16)v;
      mh2[rr] = hi; ml2[rr] = (_Float16)((v - (float)hi) * 2048.0f);
    }
    // bbp/spk stores first: start the lgkm drain while mem pack retires.
    *(half2h*)&L.bbp[grp][pn][fW][wiH] = bh2;
    *(half2h*)&L.bbp[grp][pn][fW][wiL] = bl2;
    *(half2h*)&L.spk[grp][pn][fW][wiS] = ps2;
    *(half2h*)&L.mem[grp][pn][fW][wiH] = mh2;
    *(half2h*)&L.mem[grp][pn][fW][wiL] = ml2;

    xv = xnx;
    __syncthreads();
  }

  // ---- Readout: out[b] = mem[b,:] @ Wlin + blin; per-block loss partial
  float part = memv[0] * Wlin[h0i] + memv[1] * Wlin[h0i + 1];
  part += __shfl_xor(part, 8);    // sum over side (same cc)
  part += __shfl_xor(part, 16);   // sum over q
  part += __shfl_xor(part, 32);
  if (lane < 8) L.red[grp][wg][c] = part;
  __syncthreads();
  if (tid < 16) {
    const int g = tid >> 3, b = tid & 7;
    float s = 0.0f;
#pragma unroll
    for (int ww = 0; ww < 8; ++ww) s += L.red[g][ww][b];
    float out = s + blin[0];
    float d = out - y[bbase + g * 8 + b];
    L.red2[tid] = d * d;
  }
  __syncthreads();
  if (tid == 0) {
    float s = 0.0f;
#pragma unroll
    for (int m = 0; m < MTILE; ++m) s += L.red2[m];
    wsout[blockIdx.x] = s;
  }
}

__global__ __launch_bounds__(128) void final_reduce(const float* __restrict__ part,
                                                    float* __restrict__ out) {
  __shared__ float sh[128];
  int t = threadIdx.x;
  sh[t] = part[t];
  __syncthreads();
  for (int s = 64; s > 0; s >>= 1) {
    if (t < s) sh[t] += sh[t + s];
    __syncthreads();
  }
  if (t == 0) out[0] = sh[0] * (1.0f / (float)BATCH);
}

extern "C" void kernel_launch(void* const* d_in, const int* in_sizes, int n_in,
                              void* d_out, int out_size, void* d_ws, size_t ws_size,
                              hipStream_t stream) {
  const float* x       = (const float*)d_in[0];
  const float* y       = (const float*)d_in[1];
  const float* h0m     = (const float*)d_in[2];
  const float* h0s     = (const float*)d_in[3];
  const float* h0b     = (const float*)d_in[4];
  const float* W1x     = (const float*)d_in[5];
  const float* b1x     = (const float*)d_in[6];
  const float* WtauM   = (const float*)d_in[7];
  const float* btauM   = (const float*)d_in[8];
  const float* WtauAdp = (const float*)d_in[9];
  const float* btauAdp = (const float*)d_in[10];
  const float* Wlin    = (const float*)d_in[11];
  const float* blin    = (const float*)d_in[12];
  _Float16* wsf16 = (_Float16*)d_ws;
  float* wspart = (float*)d_ws + OFF_PART_F;

  prep<<<128, 192, 0, stream>>>(W1x, b1x, WtauM, btauM, WtauAdp, btauAdp, wsf16);
  snn_main<<<NBLK, 1024, 0, stream>>>(x, y, h0m, h0s, h0b, Wlin, blin,
                                      wsf16, wspart);
  final_reduce<<<1, 128, 0, stream>>>(wspart, (float*)d_out);
}

// Round 9
// 12854.549 us; speedup vs baseline: 1.0002x; 1.0002x over previous
//
#include <hip/hip_runtime.h>
#include <math.h>

#define S_LEN 1024
#define BATCH 2048
#define MTILE 16              // 16 batches/block: two independent 8-batch groups
#define HID   128
#define NBLK  (BATCH / MTILE)   // 128 blocks, 1024 threads (16 waves) each
#define INV2048 (1.0f / 2048.0f)
#define NLOG2E (-1.44269504088896341f)   // folded into M/A gate weights

// ws layout, offsets in _Float16 elements. Ten [128][128] hi/lo weight
// arrays; M/A-gate weights are pre-scaled by -log2(e) so the sigmoid is
// rcp(1 + exp2(pre)) with a bare v_exp_f32.
#define H_M1H 0
#define H_M1L 16384
#define H_MSH 32768
#define H_MSL 49152
#define H_ASH 65536
#define H_ASL 81920
#define H_WMH 98304      // [128][128] WtauM[:,128:256] hi (scaled)
#define H_WML 114688
#define H_WBH 131072     // [128][128] WtauAdp[:,128:256] hi (scaled)
#define H_WBL 147456
// f32 ext-coefficient table: 9 arrays of [128] floats, gate-major:
// idx (gate*3 + col)*128 + h ; gate 0=d,1=M,2=A ; col 0=bias,1=x0,2=x1.
// M/A rows pre-scaled by -log2(e); d row unscaled.
#define F_EXT      81920     // float index (== 163840 halfs)
#define OFF_PART_F 83072     // float index of per-block partials [128]

typedef _Float16 half8 __attribute__((ext_vector_type(8)));
typedef _Float16 half4 __attribute__((ext_vector_type(4)));
typedef _Float16 half2h __attribute__((ext_vector_type(2)));
typedef float floatx4 __attribute__((ext_vector_type(4)));
typedef float floatx2 __attribute__((ext_vector_type(2)));

#define MFMA(a, b, c) __builtin_amdgcn_mfma_f32_16x16x32_f16((a), (b), (c), 0, 0, 0)

__device__ __forceinline__ void put_hl(_Float16* ws, int hiBase, int loBase,
                                       int idx, float v) {
  _Float16 hi = (_Float16)v;
  ws[hiBase + idx] = hi;
  ws[loBase + idx] = (_Float16)((v - (float)hi) * 2048.0f);
}

// DPP row_ror:8 == xor-8 within each 16-lane row (8 = half the 16-ring).
// VALU pipe instead of the over-subscribed LDS pipe.
__device__ __forceinline__ float dpp_xor8(float v) {
  int sw = __builtin_amdgcn_update_dpp(0, __float_as_int(v),
                                       0x128 /*row_ror:8*/, 0xF, 0xF, true);
  return __int_as_float(sw);
}

// u-scheme fold for gates with a cross term (M, A): pre-combine
// u_r = hi_r + lo_r/2048 on the natural side, then one exchange each way.
// Lane c finishes r=0,1; lane c+8 finishes r=2,3.
__device__ __forceinline__ void fold_u(floatx4 g1, floatx4 g2, bool side,
                                       float out[2]) {
  float u0 = g1[0] + g2[0] * INV2048;
  float u1 = g1[1] + g2[1] * INV2048;
  float u2 = g1[2] + g2[2] * INV2048;
  float u3 = g1[3] + g2[3] * INV2048;
  float t0 = dpp_xor8(g1[0]);   // act receives cross_0
  float t1 = dpp_xor8(g1[1]);
  float t2 = dpp_xor8(u2);      // side receives act's u2
  float t3 = dpp_xor8(u3);
  float base0 = side ? t2 : u0, add0 = side ? g1[2] : t0;
  float base1 = side ? t3 : u1, add1 = side ? g1[3] : t1;
  out[0] = base0 + add0 * INV2048;
  out[1] = base1 + add1 * INV2048;
}

// d gate: spk cols 8-15 are exactly 0 -> cross terms vanish on both sides.
__device__ __forceinline__ void fold_d(floatx4 g1, floatx4 g2, bool side,
                                       float out[2]) {
  float u0 = g1[0] + g2[0] * INV2048;
  float u1 = g1[1] + g2[1] * INV2048;
  float u2 = g1[2] + g2[2] * INV2048;
  float u3 = g1[3] + g2[3] * INV2048;
  float t2 = dpp_xor8(u2);
  float t3 = dpp_xor8(u3);
  out[0] = side ? t2 : u0;
  out[1] = side ? t3 : u1;
}

// ---- prep: fold dense->tau coupling into f16 hi/lo fragment arrays, plus
// the f32 ext-coefficient table. M/A-gate paths pre-scaled by -log2(e).
__global__ __launch_bounds__(192) void prep(
    const float* __restrict__ W1x, const float* __restrict__ b1x,
    const float* __restrict__ WtauM, const float* __restrict__ btauM,
    const float* __restrict__ WtauAdp, const float* __restrict__ btauAdp,
    _Float16* __restrict__ ws) {
  const int h = blockIdx.x, k = threadIdx.x;
  if (k >= 131) return;
  if (k < 128) {
    float w1 = W1x[h * 130 + 2 + k];
    float s1 = 0.f, s2 = 0.f;
    for (int d = 0; d < 128; ++d) {
      float wd = W1x[d * 130 + 2 + k];
      s1 += WtauM[h * 256 + d] * wd;
      s2 += WtauAdp[h * 256 + d] * wd;
    }
    put_hl(ws, H_M1H, H_M1L, h * 128 + k, w1);
    put_hl(ws, H_MSH, H_MSL, h * 128 + k, s1 * NLOG2E);
    put_hl(ws, H_ASH, H_ASL, h * 128 + k, s2 * NLOG2E);
    put_hl(ws, H_WMH, H_WML, h * 128 + k, WtauM[h * 256 + 128 + k] * NLOG2E);
    put_hl(ws, H_WBH, H_WBL, h * 128 + k, WtauAdp[h * 256 + 128 + k] * NLOG2E);
  } else {
    const int col = k - 128;   // 0: bias, 1: x0-coef, 2: x1-coef
    float m1v = (col == 0) ? b1x[h] : W1x[h * 130 + (col - 1)];
    float sm = 0.f, sa = 0.f;
    for (int d = 0; d < 128; ++d) {
      float cv = (col == 0) ? b1x[d] : W1x[d * 130 + (col - 1)];
      sm += WtauM[h * 256 + d] * cv;
      sa += WtauAdp[h * 256 + d] * cv;
    }
    if (col == 0) { sm += btauM[h]; sa += btauAdp[h]; }
    float* EXTF = (float*)ws + F_EXT;
    EXTF[(0 * 3 + col) * 128 + h] = m1v;
    EXTF[(1 * 3 + col) * 128 + h] = sm * NLOG2E;
    EXTF[(2 * 3 + col) * 128 + h] = sa * NLOG2E;
  }
}

// State slabs, PER GROUP [2]: mem/bbp per k-chunk 1 KB, half-index
// (q'*16+n')*8+j holds B[k=f*32+q'*8+j][n']; n'=0..7 hi, n'=8..15 lo(x2048).
// spk packed to the 8 real cols (512 B/chunk, no lo). Side lanes
// broadcast-read zero16 for S. Two groups = two independent recurrences
// sharing the block barrier only.
struct SLds {
  _Float16 spk[2][2][4][256];   // [grp][buf][f][..]
  _Float16 zero16[8];           // 16 B of zeros, same-address broadcast read
  _Float16 mem[2][2][4][512];
  _Float16 bbp[2][2][4][512];
  float red[2][8][8];           // [grp][wg][batch]
  float red2[16];
};

// NOTE launch bounds: hipcc's 2nd arg behaves as CUDA min-BLOCKS-per-CU
// (empirical: (512,2)->128 VGPR, (1024,4)->64 VGPR + spill catastrophe,
// round 8). One 1024-thread block/CU = 16 waves = 4/SIMD -> 128-VGPR cap,
// same per-wave budget as the 512-thread rounds.
__global__ __launch_bounds__(1024, 1) void snn_main(
    const float* __restrict__ x, const float* __restrict__ y,
    const float* __restrict__ h0m, const float* __restrict__ h0s,
    const float* __restrict__ h0b,
    const float* __restrict__ Wlin, const float* __restrict__ blin,
    const _Float16* __restrict__ W, float* __restrict__ wsout) {
  __shared__ SLds L;

  const int tid  = threadIdx.x;
  const int w    = tid >> 6;      // wave 0..15
  const int grp  = w >> 3;        // batch group 0/1 (independent recurrence)
  const int wg   = w & 7;         // wave-within-group, owns h-slice [16wg,..)
  const int lane = tid & 63;
  const int c    = lane & 15;     // A-frag m / B-frag n / C col
  const int q    = lane >> 4;
  const int cc   = c & 7;         // batch column within the group tile
  const int bbase = blockIdx.x * MTILE;
  const int bg   = bbase + grp * 8;   // this group's batch base
  const bool act  = (c < 8);
  const bool side = !act;         // side lanes own neurons r=2,3

  // ---- Register-resident A-frag weights (MFMA-only -> AGPR side)
  half8 m1h[4], m1l[4], msh[4], msl[4], ash[4], asl[4];
  half8 wmh[4], wml[4], wbh[4], wbl[4];
  {
    const int hA = wg * 16 + c;
#pragma unroll
    for (int f = 0; f < 4; ++f) {
      const int o = hA * 128 + f * 32 + q * 8;
      m1h[f] = *(const half8*)&W[H_M1H + o];
      m1l[f] = *(const half8*)&W[H_M1L + o];
      msh[f] = *(const half8*)&W[H_MSH + o];
      msl[f] = *(const half8*)&W[H_MSL + o];
      ash[f] = *(const half8*)&W[H_ASH + o];
      asl[f] = *(const half8*)&W[H_ASL + o];
      wmh[f] = *(const half8*)&W[H_WMH + o];
      wml[f] = *(const half8*)&W[H_WML + o];
      wbh[f] = *(const half8*)&W[H_WBH + o];
      wbl[f] = *(const half8*)&W[H_WBL + o];
    }
  }

  if (tid == 0) {   // 16 B zero block for c>=8 broadcast S reads
    *(half8*)&L.zero16[0] = half8{0, 0, 0, 0, 0, 0, 0, 0};
  }

  // ---- f32 ext coefficients for this lane's 2 neurons (h0i, h0i+1)
  const int h0i = wg * 16 + q * 4 + (side ? 2 : 0);
  const float* CF = (const float*)W + F_EXT;
  floatx2 cd0 = *(const floatx2*)&CF[0 * 128 + h0i];
  floatx2 cd1 = *(const floatx2*)&CF[1 * 128 + h0i];
  floatx2 cd2 = *(const floatx2*)&CF[2 * 128 + h0i];
  floatx2 cm0 = *(const floatx2*)&CF[3 * 128 + h0i];
  floatx2 cm1 = *(const floatx2*)&CF[4 * 128 + h0i];
  floatx2 cm2 = *(const floatx2*)&CF[5 * 128 + h0i];
  floatx2 ca0 = *(const floatx2*)&CF[6 * 128 + h0i];
  floatx2 ca1 = *(const floatx2*)&CF[7 * 128 + h0i];
  floatx2 ca2 = *(const floatx2*)&CF[8 * 128 + h0i];

  // ---- Per-lane recurrent state: EVERY lane owns 2 neurons.
  float memv[2], spk[2], bb[2];
  {
    const int gi = (bg + cc) * HID + h0i;
    float2 tm = *(const float2*)&h0m[gi];
    float2 ts = *(const float2*)&h0s[gi];
    float2 tb = *(const float2*)&h0b[gi];
    memv[0] = tm.x; memv[1] = tm.y;
    spk[0]  = ts.x; spk[1]  = ts.y;
    bb[0]   = tb.x; bb[1]   = tb.y;
  }

  // State value (h = wg*16+q*4+side*2+rr) enters GEMM2 as B[k=h][n]:
  // chunk fW = wg>>1, granule qp = (wg&1)*2 + (q>>1), j = (q&1)*4+side*2+rr.
  const int fW  = wg >> 1;
  const int qp  = (wg & 1) * 2 + (q >> 1);
  const int jo  = (q & 1) * 4 + (side ? 2 : 0);
  const int wiH = (qp * 16 + cc) * 8 + jo;        // mem/bbp hi (n'=cc)
  const int wiL = wiH + 64;                       // mem/bbp lo (n'=cc+8)
  const int wiS = (qp * 8 + cc) * 8 + jo;         // packed spk
  const int ri  = lane * 8;                       // mem/bbp read (identity)
  const _Float16* spkB0 = act ? &L.spk[grp][0][0][(q * 8 + cc) * 8] : L.zero16;
  const _Float16* spkB1 = act ? &L.spk[grp][1][0][(q * 8 + cc) * 8] : L.zero16;
  const int spkStep = act ? 256 : 0;

  {   // initial state into buf 0 (all lanes, 2 values each)
    half2h ps2, mh2, ml2, bh2, bl2;
#pragma unroll
    for (int rr = 0; rr < 2; ++rr) {
      ps2[rr] = (_Float16)spk[rr];
      float v = memv[rr]; _Float16 hi = (_Float16)v;
      mh2[rr] = hi; ml2[rr] = (_Float16)((v - (float)hi) * 2048.0f);
      v = bb[rr]; hi = (_Float16)v;
      bh2[rr] = hi; bl2[rr] = (_Float16)((v - (float)hi) * 2048.0f);
    }
    *(half2h*)&L.spk[grp][0][fW][wiS] = ps2;
    *(half2h*)&L.mem[grp][0][fW][wiH] = mh2;
    *(half2h*)&L.mem[grp][0][fW][wiL] = ml2;
    *(half2h*)&L.bbp[grp][0][fW][wiH] = bh2;
    *(half2h*)&L.bbp[grp][0][fW][wiL] = bl2;
  }
  __syncthreads();

  // Per-lane x stream for batch bg+cc, prefetched one step ahead.
  const float* xb = x + (size_t)(bg + cc) * 2;
  float2 xv = *(const float2*)xb;   // x at t=0

#pragma unroll 1
  for (int t = 0; t < S_LEN; ++t) {
    const int p = t & 1, pn = p ^ 1;
    const size_t tn = (t + 1 < S_LEN) ? (size_t)(t + 1) : (size_t)t;
    float2 xnx = *(const float2*)(xb + tn * (size_t)(BATCH * 2));  // prefetch

    const _Float16* sB = p ? spkB1 : spkB0;

    floatx4 d1 = {0.f,0.f,0.f,0.f}, d2 = {0.f,0.f,0.f,0.f};
    floatx4 m1 = {0.f,0.f,0.f,0.f}, m2 = {0.f,0.f,0.f,0.f};
    floatx4 a1 = {0.f,0.f,0.f,0.f}, a2 = {0.f,0.f,0.f,0.f};

#pragma unroll
    for (int f = 0; f < 4; ++f) {
      half8 S = *(const half8*)&sB[f * spkStep];        // [spk] (0 for c>=8)
      half8 M = *(const half8*)&L.mem[grp][p][f][ri];   // [mh  | ml]
      half8 B = *(const half8*)&L.bbp[grp][p][f][ri];   // [bh  | bl]
      d1 = MFMA(m1h[f], S, d1);
      d2 = MFMA(m1l[f], S, d2);
      m1 = MFMA(msh[f], S, m1);
      m1 = MFMA(wmh[f], M, m1);    // cols0-7: wmh*mh ; cols8-15: wmh*ml
      m2 = MFMA(msl[f], S, m2);
      m2 = MFMA(wml[f], M, m2);    // cols0-7: wml*mh ; cols8-15: junk
      a1 = MFMA(ash[f], S, a1);
      a1 = MFMA(wbh[f], B, a1);
      a2 = MFMA(asl[f], S, a2);
      a2 = MFMA(wbl[f], B, a2);
    }

    const float xc0 = xv.x, xc1 = xv.y;

    // M gate first: its exp2 issues while the a/d folds run on the VALU.
    float preM[2], preA[2], den[2];
    fold_u(m1, m2, side, preM);
    float pM0 = preM[0] + cm0[0] + cm1[0] * xc0 + cm2[0] * xc1;
    float pM1 = preM[1] + cm0[1] + cm1[1] * xc0 + cm2[1] * xc1;
    float eM0 = __builtin_amdgcn_exp2f(pM0);   // weights pre-scaled by -log2e
    float eM1 = __builtin_amdgcn_exp2f(pM1);
    fold_u(a1, a2, side, preA);
    float pA0 = preA[0] + ca0[0] + ca1[0] * xc0 + ca2[0] * xc1;
    float pA1 = preA[1] + ca0[1] + ca1[1] * xc0 + ca2[1] * xc1;
    float eA0 = __builtin_amdgcn_exp2f(pA0);
    float eA1 = __builtin_amdgcn_exp2f(pA1);
    fold_d(d1, d2, side, den);

    float tM[2] = { __builtin_amdgcn_rcpf(1.0f + eM0),
                    __builtin_amdgcn_rcpf(1.0f + eM1) };
    float tA[2] = { __builtin_amdgcn_rcpf(1.0f + eA0),
                    __builtin_amdgcn_rcpf(1.0f + eA1) };

    // ---- Elementwise update: 2 real neurons per lane (64 lanes busy).
    half2h ps2, mh2, ml2, bh2, bl2;
#pragma unroll
    for (int rr = 0; rr < 2; ++rr) {
      float dv = den[rr] + cd0[rr] + cd1[rr] * xc0 + cd2[rr] * xc1;
      bb[rr] = tA[rr] * bb[rr] + (1.0f - tA[rr]) * spk[rr];
      float Bth = 0.01f + 1.8f * bb[rr];
      memv[rr] = memv[rr] * tM[rr] + (1.0f - tM[rr]) * dv - Bth * spk[rr];
      spk[rr] = (memv[rr] - Bth) > 0.0f ? 1.0f : 0.0f;
      ps2[rr] = (_Float16)spk[rr];
      float v = bb[rr]; _Float16 hi = (_Float16)v;
      bh2[rr] = hi; bl2[rr] = (_Float16)((v - (float)hi) * 2048.0f);
      v = memv[rr]; hi = (_Float16)v;
      mh2[rr] = hi; ml2[rr] = (_Float16)((v - (float)hi) * 2048.0f);
    }
    // bbp/spk stores first: start the lgkm drain while mem pack retires.
    *(half2h*)&L.bbp[grp][pn][fW][wiH] = bh2;
    *(half2h*)&L.bbp[grp][pn][fW][wiL] = bl2;
    *(half2h*)&L.spk[grp][pn][fW][wiS] = ps2;
    *(half2h*)&L.mem[grp][pn][fW][wiH] = mh2;
    *(half2h*)&L.mem[grp][pn][fW][wiL] = ml2;

    xv = xnx;
    __syncthreads();
  }

  // ---- Readout: out[b] = mem[b,:] @ Wlin + blin; per-block loss partial
  float part = memv[0] * Wlin[h0i] + memv[1] * Wlin[h0i + 1];
  part += __shfl_xor(part, 8);    // sum over side (same cc)
  part += __shfl_xor(part, 16);   // sum over q
  part += __shfl_xor(part, 32);
  if (lane < 8) L.red[grp][wg][c] = part;
  __syncthreads();
  if (tid < 16) {
    const int g = tid >> 3, b = tid & 7;
    float s = 0.0f;
#pragma unroll
    for (int ww = 0; ww < 8; ++ww) s += L.red[g][ww][b];
    float out = s + blin[0];
    float d = out - y[bbase + g * 8 + b];
    L.red2[tid] = d * d;
  }
  __syncthreads();
  if (tid == 0) {
    float s = 0.0f;
#pragma unroll
    for (int m = 0; m < MTILE; ++m) s += L.red2[m];
    wsout[blockIdx.x] = s;
  }
}

__global__ __launch_bounds__(128) void final_reduce(const float* __restrict__ part,
                                                    float* __restrict__ out) {
  __shared__ float sh[128];
  int t = threadIdx.x;
  sh[t] = part[t];
  __syncthreads();
  for (int s = 64; s > 0; s >>= 1) {
    if (t < s) sh[t] += sh[t + s];
    __syncthreads();
  }
  if (t == 0) out[0] = sh[0] * (1.0f / (float)BATCH);
}

extern "C" void kernel_launch(void* const* d_in, const int* in_sizes, int n_in,
                              void* d_out, int out_size, void* d_ws, size_t ws_size,
                              hipStream_t stream) {
  const float* x       = (const float*)d_in[0];
  const float* y       = (const float*)d_in[1];
  const float* h0m     = (const float*)d_in[2];
  const float* h0s     = (const float*)d_in[3];
  const float* h0b     = (const float*)d_in[4];
  const float* W1x     = (const float*)d_in[5];
  const float* b1x     = (const float*)d_in[6];
  const float* WtauM   = (const float*)d_in[7];
  const float* btauM   = (const float*)d_in[8];
  const float* WtauAdp = (const float*)d_in[9];
  const float* btauAdp = (const float*)d_in[10];
  const float* Wlin    = (const float*)d_in[11];
  const float* blin    = (const float*)d_in[12];
  _Float16* wsf16 = (_Float16*)d_ws;
  float* wspart = (float*)d_ws + OFF_PART_F;

  prep<<<128, 192, 0, stream>>>(W1x, b1x, WtauM, btauM, WtauAdp, btauAdp, wsf16);
  snn_main<<<NBLK, 1024, 0, stream>>>(x, y, h0m, h0s, h0b, Wlin, blin,
                                      wsf16, wspart);
  final_reduce<<<1, 128, 0, stream>>>(wspart, (float*)d_out);
}

// Round 11
// 3715.824 us; speedup vs baseline: 3.4602x; 3.4594x over previous
//
#include <hip/hip_runtime.h>
#include <math.h>

#define S_LEN 1024
#define BATCH 2048
#define MTILE 16              // two independent 8-batch groups per block
#define HID   128
#define NBLK  (BATCH / MTILE)   // 128 blocks, 512 threads (8 waves) each
#define INV2048 (1.0f / 2048.0f)
#define NLOG2E (-1.44269504088896341f)   // folded into M/A gate weights

// ws layout, offsets in _Float16 elements. Ten [128][128] hi/lo weight
// arrays; M/A-gate weights pre-scaled by -log2(e): sigmoid = rcp(1+exp2(.)).
#define H_M1H 0
#define H_M1L 16384
#define H_MSH 32768
#define H_MSL 49152
#define H_ASH 65536
#define H_ASL 81920
#define H_WMH 98304      // [128][128] WtauM[:,128:256] hi (scaled)
#define H_WML 114688
#define H_WBH 131072     // [128][128] WtauAdp[:,128:256] hi (scaled)
#define H_WBL 147456
// f32 ext-coefficient table: 9 arrays of [128] floats, gate-major.
#define F_EXT      81920     // float index (== 163840 halfs)
#define OFF_PART_F 83072     // float index of per-block partials [128]

typedef _Float16 half8 __attribute__((ext_vector_type(8)));
typedef _Float16 half2h __attribute__((ext_vector_type(2)));
typedef float floatx4 __attribute__((ext_vector_type(4)));
typedef float floatx2 __attribute__((ext_vector_type(2)));

#define MFMA(a, b, c) __builtin_amdgcn_mfma_f32_16x16x32_f16((a), (b), (c), 0, 0, 0)

__device__ __forceinline__ void put_hl(_Float16* ws, int hiBase, int loBase,
                                       int idx, float v) {
  _Float16 hi = (_Float16)v;
  ws[hiBase + idx] = hi;
  ws[loBase + idx] = (_Float16)((v - (float)hi) * 2048.0f);
}

// DPP row_ror:8 == xor-8 within each 16-lane row.
__device__ __forceinline__ float dpp_xor8(float v) {
  int sw = __builtin_amdgcn_update_dpp(0, __float_as_int(v),
                                       0x128 /*row_ror:8*/, 0xF, 0xF, true);
  return __int_as_float(sw);
}

// u-scheme fold (M, A gates). Lane c finishes r=0,1; lane c+8 r=2,3.
__device__ __forceinline__ void fold_u(floatx4 g1, floatx4 g2, bool side,
                                       float out[2]) {
  float u0 = g1[0] + g2[0] * INV2048;
  float u1 = g1[1] + g2[1] * INV2048;
  float u2 = g1[2] + g2[2] * INV2048;
  float u3 = g1[3] + g2[3] * INV2048;
  float t0 = dpp_xor8(g1[0]);
  float t1 = dpp_xor8(g1[1]);
  float t2 = dpp_xor8(u2);
  float t3 = dpp_xor8(u3);
  float base0 = side ? t2 : u0, add0 = side ? g1[2] : t0;
  float base1 = side ? t3 : u1, add1 = side ? g1[3] : t1;
  out[0] = base0 + add0 * INV2048;
  out[1] = base1 + add1 * INV2048;
}

// d gate: spk cols 8-15 exactly 0 -> no cross terms.
__device__ __forceinline__ void fold_d(floatx4 g1, floatx4 g2, bool side,
                                       float out[2]) {
  float u0 = g1[0] + g2[0] * INV2048;
  float u1 = g1[1] + g2[1] * INV2048;
  float u2 = g1[2] + g2[2] * INV2048;
  float u3 = g1[3] + g2[3] * INV2048;
  float t2 = dpp_xor8(u2);
  float t3 = dpp_xor8(u3);
  out[0] = side ? t2 : u0;
  out[1] = side ? t3 : u1;
}

// ---- prep (unchanged from round 7)
__global__ __launch_bounds__(192) void prep(
    const float* __restrict__ W1x, const float* __restrict__ b1x,
    const float* __restrict__ WtauM, const float* __restrict__ btauM,
    const float* __restrict__ WtauAdp, const float* __restrict__ btauAdp,
    _Float16* __restrict__ ws) {
  const int h = blockIdx.x, k = threadIdx.x;
  if (k >= 131) return;
  if (k < 128) {
    float w1 = W1x[h * 130 + 2 + k];
    float s1 = 0.f, s2 = 0.f;
    for (int d = 0; d < 128; ++d) {
      float wd = W1x[d * 130 + 2 + k];
      s1 += WtauM[h * 256 + d] * wd;
      s2 += WtauAdp[h * 256 + d] * wd;
    }
    put_hl(ws, H_M1H, H_M1L, h * 128 + k, w1);
    put_hl(ws, H_MSH, H_MSL, h * 128 + k, s1 * NLOG2E);
    put_hl(ws, H_ASH, H_ASL, h * 128 + k, s2 * NLOG2E);
    put_hl(ws, H_WMH, H_WML, h * 128 + k, WtauM[h * 256 + 128 + k] * NLOG2E);
    put_hl(ws, H_WBH, H_WBL, h * 128 + k, WtauAdp[h * 256 + 128 + k] * NLOG2E);
  } else {
    const int col = k - 128;
    float m1v = (col == 0) ? b1x[h] : W1x[h * 130 + (col - 1)];
    float sm = 0.f, sa = 0.f;
    for (int d = 0; d < 128; ++d) {
      float cv = (col == 0) ? b1x[d] : W1x[d * 130 + (col - 1)];
      sm += WtauM[h * 256 + d] * cv;
      sa += WtauAdp[h * 256 + d] * cv;
    }
    if (col == 0) { sm += btauM[h]; sa += btauAdp[h]; }
    float* EXTF = (float*)ws + F_EXT;
    EXTF[(0 * 3 + col) * 128 + h] = m1v;
    EXTF[(1 * 3 + col) * 128 + h] = sm * NLOG2E;
    EXTF[(2 * 3 + col) * 128 + h] = sa * NLOG2E;
  }
}

// State slabs PER GROUP: two independent recurrences share the block
// barrier and the per-wave weight registers; nothing else.
struct SLds {
  _Float16 spk[2][2][4][256];   // [grp][buf][f][..] packed 8 cols
  _Float16 zero16[8];
  _Float16 mem[2][2][4][512];
  _Float16 bbp[2][2][4][512];
  float red[2][8][8];           // [grp][wg][batch]
  float red2[16];
};

// 512 threads, 2 blocks/CU declared -> 128 arch-VGPR cap (known-good).
__global__ __launch_bounds__(512, 2) void snn_main(
    const float* __restrict__ x, const float* __restrict__ y,
    const float* __restrict__ h0m, const float* __restrict__ h0s,
    const float* __restrict__ h0b,
    const float* __restrict__ Wlin, const float* __restrict__ blin,
    const _Float16* __restrict__ W, float* __restrict__ wsout) {
  __shared__ SLds L;

  const int tid  = threadIdx.x;
  const int wg   = tid >> 6;      // wave 0..7, owns h-slice [16wg, 16wg+16)
  const int lane = tid & 63;
  const int c    = lane & 15;
  const int q    = lane >> 4;
  const int cc   = c & 7;
  const int bbase = blockIdx.x * MTILE;
  const bool act  = (c < 8);
  const bool side = !act;

  // ---- Register-resident A-frag weights, SHARED by both groups
  half8 m1h[4], m1l[4], msh[4], msl[4], ash[4], asl[4];
  half8 wmh[4], wml[4], wbh[4], wbl[4];
  {
    const int hA = wg * 16 + c;
#pragma unroll
    for (int f = 0; f < 4; ++f) {
      const int o = hA * 128 + f * 32 + q * 8;
      m1h[f] = *(const half8*)&W[H_M1H + o];
      m1l[f] = *(const half8*)&W[H_M1L + o];
      msh[f] = *(const half8*)&W[H_MSH + o];
      msl[f] = *(const half8*)&W[H_MSL + o];
      ash[f] = *(const half8*)&W[H_ASH + o];
      asl[f] = *(const half8*)&W[H_ASL + o];
      wmh[f] = *(const half8*)&W[H_WMH + o];
      wml[f] = *(const half8*)&W[H_WML + o];
      wbh[f] = *(const half8*)&W[H_WBH + o];
      wbl[f] = *(const half8*)&W[H_WBL + o];
    }
  }

  if (tid == 0) {
    *(half8*)&L.zero16[0] = half8{0, 0, 0, 0, 0, 0, 0, 0};
  }

  // ---- f32 ext coefficients (shared by both groups; same h)
  const int h0i = wg * 16 + q * 4 + (side ? 2 : 0);
  const float* CF = (const float*)W + F_EXT;
  floatx2 cd0 = *(const floatx2*)&CF[0 * 128 + h0i];
  floatx2 cd1 = *(const floatx2*)&CF[1 * 128 + h0i];
  floatx2 cd2 = *(const floatx2*)&CF[2 * 128 + h0i];
  floatx2 cm0 = *(const floatx2*)&CF[3 * 128 + h0i];
  floatx2 cm1 = *(const floatx2*)&CF[4 * 128 + h0i];
  floatx2 cm2 = *(const floatx2*)&CF[5 * 128 + h0i];
  floatx2 ca0 = *(const floatx2*)&CF[6 * 128 + h0i];
  floatx2 ca1 = *(const floatx2*)&CF[7 * 128 + h0i];
  floatx2 ca2 = *(const floatx2*)&CF[8 * 128 + h0i];

  // ---- Per-lane state for BOTH groups (2 neurons each)
  float memA[2], spkA[2], bbA[2], memB[2], spkB[2], bbB[2];
  {
    const int giA = (bbase + cc) * HID + h0i;
    const int giB = (bbase + 8 + cc) * HID + h0i;
    float2 t0, t1;
    t0 = *(const float2*)&h0m[giA]; memA[0] = t0.x; memA[1] = t0.y;
    t1 = *(const float2*)&h0m[giB]; memB[0] = t1.x; memB[1] = t1.y;
    t0 = *(const float2*)&h0s[giA]; spkA[0] = t0.x; spkA[1] = t0.y;
    t1 = *(const float2*)&h0s[giB]; spkB[0] = t1.x; spkB[1] = t1.y;
    t0 = *(const float2*)&h0b[giA]; bbA[0] = t0.x; bbA[1] = t0.y;
    t1 = *(const float2*)&h0b[giB]; bbB[0] = t1.x; bbB[1] = t1.y;
  }

  const int fW  = wg >> 1;
  const int qp  = (wg & 1) * 2 + (q >> 1);
  const int jo  = (q & 1) * 4 + (side ? 2 : 0);
  const int wiH = (qp * 16 + cc) * 8 + jo;
  const int wiL = wiH + 64;
  const int wiS = (qp * 8 + cc) * 8 + jo;
  const int ri  = lane * 8;
  const _Float16* spkA0 = act ? &L.spk[0][0][0][(q * 8 + cc) * 8] : L.zero16;
  const _Float16* spkA1 = act ? &L.spk[0][1][0][(q * 8 + cc) * 8] : L.zero16;
  const _Float16* spkB0 = act ? &L.spk[1][0][0][(q * 8 + cc) * 8] : L.zero16;
  const _Float16* spkB1 = act ? &L.spk[1][1][0][(q * 8 + cc) * 8] : L.zero16;
  const int spkStep = act ? 256 : 0;

  {   // initial state into buf 0, both groups
    half2h ps2, mh2, ml2, bh2, bl2;
#pragma unroll
    for (int rr = 0; rr < 2; ++rr) {
      ps2[rr] = (_Float16)spkA[rr];
      float v = memA[rr]; _Float16 hi = (_Float16)v;
      mh2[rr] = hi; ml2[rr] = (_Float16)((v - (float)hi) * 2048.0f);
      v = bbA[rr]; hi = (_Float16)v;
      bh2[rr] = hi; bl2[rr] = (_Float16)((v - (float)hi) * 2048.0f);
    }
    *(half2h*)&L.spk[0][0][fW][wiS] = ps2;
    *(half2h*)&L.mem[0][0][fW][wiH] = mh2; *(half2h*)&L.mem[0][0][fW][wiL] = ml2;
    *(half2h*)&L.bbp[0][0][fW][wiH] = bh2; *(half2h*)&L.bbp[0][0][fW][wiL] = bl2;
#pragma unroll
    for (int rr = 0; rr < 2; ++rr) {
      ps2[rr] = (_Float16)spkB[rr];
      float v = memB[rr]; _Float16 hi = (_Float16)v;
      mh2[rr] = hi; ml2[rr] = (_Float16)((v - (float)hi) * 2048.0f);
      v = bbB[rr]; hi = (_Float16)v;
      bh2[rr] = hi; bl2[rr] = (_Float16)((v - (float)hi) * 2048.0f);
    }
    *(half2h*)&L.spk[1][0][fW][wiS] = ps2;
    *(half2h*)&L.mem[1][0][fW][wiH] = mh2; *(half2h*)&L.mem[1][0][fW][wiL] = ml2;
    *(half2h*)&L.bbp[1][0][fW][wiH] = bh2; *(half2h*)&L.bbp[1][0][fW][wiL] = bl2;
  }
  __syncthreads();

  // x streams for both groups, prefetched one step ahead.
  const float* xbA = x + (size_t)(bbase + cc) * 2;
  const float* xbB = xbA + 16;   // +8 batches
  float2 xvA = *(const float2*)xbA;
  float2 xvB = *(const float2*)xbB;

#pragma unroll 1
  for (int t = 0; t < S_LEN; ++t) {
    const int p = t & 1, pn = p ^ 1;
    const size_t tn = (t + 1 < S_LEN) ? (size_t)(t + 1) : (size_t)t;
    float2 xnA = *(const float2*)(xbA + tn * (size_t)(BATCH * 2));
    float2 xnB = *(const float2*)(xbB + tn * (size_t)(BATCH * 2));

    const _Float16* sBA = p ? spkA1 : spkA0;
    const _Float16* sBB = p ? spkB1 : spkB0;

    floatx4 d1A = {0,0,0,0}, d2A = {0,0,0,0}, m1A = {0,0,0,0},
            m2A = {0,0,0,0}, a1A = {0,0,0,0}, a2A = {0,0,0,0};
    floatx4 d1B = {0,0,0,0}, d2B = {0,0,0,0}, m1B = {0,0,0,0},
            m2B = {0,0,0,0}, a1B = {0,0,0,0}, a2B = {0,0,0,0};

    // Dual GEMM: per f, interleaved A/B -- two fully independent
    // dependency-chain sets keep the matrix pipe saturated.
#pragma unroll
    for (int f = 0; f < 4; ++f) {
      half8 SA = *(const half8*)&sBA[f * spkStep];
      half8 MA = *(const half8*)&L.mem[0][p][f][ri];
      half8 BA = *(const half8*)&L.bbp[0][p][f][ri];
      half8 SB = *(const half8*)&sBB[f * spkStep];
      half8 MB = *(const half8*)&L.mem[1][p][f][ri];
      half8 BB = *(const half8*)&L.bbp[1][p][f][ri];
      d1A = MFMA(m1h[f], SA, d1A);
      d1B = MFMA(m1h[f], SB, d1B);
      d2A = MFMA(m1l[f], SA, d2A);
      d2B = MFMA(m1l[f], SB, d2B);
      m1A = MFMA(msh[f], SA, m1A);
      m1B = MFMA(msh[f], SB, m1B);
      m1A = MFMA(wmh[f], MA, m1A);
      m1B = MFMA(wmh[f], MB, m1B);
      m2A = MFMA(msl[f], SA, m2A);
      m2B = MFMA(msl[f], SB, m2B);
      m2A = MFMA(wml[f], MA, m2A);
      m2B = MFMA(wml[f], MB, m2B);
      a1A = MFMA(ash[f], SA, a1A);
      a1B = MFMA(ash[f], SB, a1B);
      a1A = MFMA(wbh[f], BA, a1A);
      a1B = MFMA(wbh[f], BB, a1B);
      a2A = MFMA(asl[f], SA, a2A);
      a2B = MFMA(asl[f], SB, a2B);
      a2A = MFMA(wbl[f], BA, a2A);
      a2B = MFMA(wbl[f], BB, a2B);
    }

    // Dual elementwise: interleaved A/B doubles ILP through the serial
    // fold -> exp2 -> rcp -> update chain.
    float preM_A[2], preA_A[2], den_A[2];
    float preM_B[2], preA_B[2], den_B[2];
    fold_u(m1A, m2A, side, preM_A);
    fold_u(m1B, m2B, side, preM_B);
    float pM0A = preM_A[0] + cm0[0] + cm1[0] * xvA.x + cm2[0] * xvA.y;
    float pM1A = preM_A[1] + cm0[1] + cm1[1] * xvA.x + cm2[1] * xvA.y;
    float pM0B = preM_B[0] + cm0[0] + cm1[0] * xvB.x + cm2[0] * xvB.y;
    float pM1B = preM_B[1] + cm0[1] + cm1[1] * xvB.x + cm2[1] * xvB.y;
    float eM0A = __builtin_amdgcn_exp2f(pM0A);
    float eM1A = __builtin_amdgcn_exp2f(pM1A);
    float eM0B = __builtin_amdgcn_exp2f(pM0B);
    float eM1B = __builtin_amdgcn_exp2f(pM1B);
    fold_u(a1A, a2A, side, preA_A);
    fold_u(a1B, a2B, side, preA_B);
    float pA0A = preA_A[0] + ca0[0] + ca1[0] * xvA.x + ca2[0] * xvA.y;
    float pA1A = preA_A[1] + ca0[1] + ca1[1] * xvA.x + ca2[1] * xvA.y;
    float pA0B = preA_B[0] + ca0[0] + ca1[0] * xvB.x + ca2[0] * xvB.y;
    float pA1B = preA_B[1] + ca0[1] + ca1[1] * xvB.x + ca2[1] * xvB.y;
    float eA0A = __builtin_amdgcn_exp2f(pA0A);
    float eA1A = __builtin_amdgcn_exp2f(pA1A);
    float eA0B = __builtin_amdgcn_exp2f(pA0B);
    float eA1B = __builtin_amdgcn_exp2f(pA1B);
    fold_d(d1A, d2A, side, den_A);
    fold_d(d1B, d2B, side, den_B);

    float tMA[2] = { __builtin_amdgcn_rcpf(1.0f + eM0A),
                     __builtin_amdgcn_rcpf(1.0f + eM1A) };
    float tMB[2] = { __builtin_amdgcn_rcpf(1.0f + eM0B),
                     __builtin_amdgcn_rcpf(1.0f + eM1B) };
    float tAA[2] = { __builtin_amdgcn_rcpf(1.0f + eA0A),
                     __builtin_amdgcn_rcpf(1.0f + eA1A) };
    float tAB[2] = { __builtin_amdgcn_rcpf(1.0f + eA0B),
                     __builtin_amdgcn_rcpf(1.0f + eA1B) };

    half2h psA, mhA, mlA, bhA, blA, psB, mhB, mlB, bhB, blB;
#pragma unroll
    for (int rr = 0; rr < 2; ++rr) {
      float dvA = den_A[rr] + cd0[rr] + cd1[rr] * xvA.x + cd2[rr] * xvA.y;
      float dvB = den_B[rr] + cd0[rr] + cd1[rr] * xvB.x + cd2[rr] * xvB.y;
      bbA[rr] = tAA[rr] * bbA[rr] + (1.0f - tAA[rr]) * spkA[rr];
      bbB[rr] = tAB[rr] * bbB[rr] + (1.0f - tAB[rr]) * spkB[rr];
      float BthA = 0.01f + 1.8f * bbA[rr];
      float BthB = 0.01f + 1.8f * bbB[rr];
      memA[rr] = memA[rr] * tMA[rr] + (1.0f - tMA[rr]) * dvA - BthA * spkA[rr];
      memB[rr] = memB[rr] * tMB[rr] + (1.0f - tMB[rr]) * dvB - BthB * spkB[rr];
      spkA[rr] = (memA[rr] - BthA) > 0.0f ? 1.0f : 0.0f;
      spkB[rr] = (memB[rr] - BthB) > 0.0f ? 1.0f : 0.0f;
      psA[rr] = (_Float16)spkA[rr];
      psB[rr] = (_Float16)spkB[rr];
      float v = bbA[rr]; _Float16 hi = (_Float16)v;
      bhA[rr] = hi; blA[rr] = (_Float16)((v - (float)hi) * 2048.0f);
      v = bbB[rr]; hi = (_Float16)v;
      bhB[rr] = hi; blB[rr] = (_Float16)((v - (float)hi) * 2048.0f);
      v = memA[rr]; hi = (_Float16)v;
      mhA[rr] = hi; mlA[rr] = (_Float16)((v - (float)hi) * 2048.0f);
      v = memB[rr]; hi = (_Float16)v;
      mhB[rr] = hi; mlB[rr] = (_Float16)((v - (float)hi) * 2048.0f);
    }
    *(half2h*)&L.bbp[0][pn][fW][wiH] = bhA;
    *(half2h*)&L.bbp[0][pn][fW][wiL] = blA;
    *(half2h*)&L.bbp[1][pn][fW][wiH] = bhB;
    *(half2h*)&L.bbp[1][pn][fW][wiL] = blB;
    *(half2h*)&L.spk[0][pn][fW][wiS] = psA;
    *(half2h*)&L.spk[1][pn][fW][wiS] = psB;
    *(half2h*)&L.mem[0][pn][fW][wiH] = mhA;
    *(half2h*)&L.mem[0][pn][fW][wiL] = mlA;
    *(half2h*)&L.mem[1][pn][fW][wiH] = mhB;
    *(half2h*)&L.mem[1][pn][fW][wiL] = mlB;

    xvA = xnA; xvB = xnB;
    __syncthreads();
  }

  // ---- Readout, both groups
  float pA = memA[0] * Wlin[h0i] + memA[1] * Wlin[h0i + 1];
  float pB = memB[0] * Wlin[h0i] + memB[1] * Wlin[h0i + 1];
  pA += __shfl_xor(pA, 8);  pB += __shfl_xor(pB, 8);
  pA += __shfl_xor(pA, 16); pB += __shfl_xor(pB, 16);
  pA += __shfl_xor(pA, 32); pB += __shfl_xor(pB, 32);
  if (lane < 8) { L.red[0][wg][c] = pA; L.red[1][wg][c] = pB; }
  __syncthreads();
  if (tid < 16) {
    const int g = tid >> 3, b = tid & 7;
    float s = 0.0f;
#pragma unroll
    for (int ww = 0; ww < 8; ++ww) s += L.red[g][ww][b];
    float out = s + blin[0];
    float d = out - y[bbase + g * 8 + b];
    L.red2[tid] = d * d;
  }
  __syncthreads();
  if (tid == 0) {
    float s = 0.0f;
#pragma unroll
    for (int m = 0; m < MTILE; ++m) s += L.red2[m];
    wsout[blockIdx.x] = s;
  }
}

__global__ __launch_bounds__(128) void final_reduce(const float* __restrict__ part,
                                                    float* __restrict__ out) {
  __shared__ float sh[128];
  int t = threadIdx.x;
  sh[t] = part[t];
  __syncthreads();
  for (int s = 64; s > 0; s >>= 1) {
    if (t < s) sh[t] += sh[t + s];
    __syncthreads();
  }
  if (t == 0) out[0] = sh[0] * (1.0f / (float)BATCH);
}

extern "C" void kernel_launch(void* const* d_in, const int* in_sizes, int n_in,
                              void* d_out, int out_size, void* d_ws, size_t ws_size,
                              hipStream_t stream) {
  const float* x       = (const float*)d_in[0];
  const float* y       = (const float*)d_in[1];
  const float* h0m     = (const float*)d_in[2];
  const float* h0s     = (const float*)d_in[3];
  const float* h0b     = (const float*)d_in[4];
  const float* W1x     = (const float*)d_in[5];
  const float* b1x     = (const float*)d_in[6];
  const float* WtauM   = (const float*)d_in[7];
  const float* btauM   = (const float*)d_in[8];
  const float* WtauAdp = (const float*)d_in[9];
  const float* btauAdp = (const float*)d_in[10];
  const float* Wlin    = (const float*)d_in[11];
  const float* blin    = (const float*)d_in[12];
  _Float16* wsf16 = (_Float16*)d_ws;
  float* wspart = (float*)d_ws + OFF_PART_F;

  prep<<<128, 192, 0, stream>>>(W1x, b1x, WtauM, btauM, WtauAdp, btauAdp, wsf16);
  snn_main<<<NBLK, 512, 0, stream>>>(x, y, h0m, h0s, h0b, Wlin, blin,
                                     wsf16, wspart);
  final_reduce<<<1, 128, 0, stream>>>(wspart, (float*)d_out);
}

// Round 12
// 3222.666 us; speedup vs baseline: 3.9898x; 1.1530x over previous
//
#include <hip/hip_runtime.h>
#include <math.h>

#define S_LEN 1024
#define BATCH 2048
#define MTILE 16              // two independent 8-batch groups per block
#define HID   128
#define NBLK  (BATCH / MTILE)   // 128 blocks, 512 threads (8 waves) each
#define INV2048 (1.0f / 2048.0f)
#define NLOG2E (-1.44269504088896341f)   // folded into M/A gate weights

// ws layout, offsets in _Float16 elements. Ten [128][128] hi/lo weight
// arrays; M/A-gate weights pre-scaled by -log2(e): sigmoid = rcp(1+exp2(.)).
#define H_M1H 0
#define H_M1L 16384
#define H_MSH 32768
#define H_MSL 49152
#define H_ASH 65536
#define H_ASL 81920
#define H_WMH 98304      // [128][128] WtauM[:,128:256] hi (scaled)
#define H_WML 114688
#define H_WBH 131072     // [128][128] WtauAdp[:,128:256] hi (scaled)
#define H_WBL 147456
// f32 ext-coefficient table: 9 arrays of [128] floats, gate-major.
#define F_EXT      81920     // float index (== 163840 halfs)
#define OFF_PART_F 83072     // float index of per-block partials [128]

typedef _Float16 half8 __attribute__((ext_vector_type(8)));
typedef _Float16 half2h __attribute__((ext_vector_type(2)));
typedef float floatx4 __attribute__((ext_vector_type(4)));
typedef float floatx2 __attribute__((ext_vector_type(2)));

#define MFMA(a, b, c) __builtin_amdgcn_mfma_f32_16x16x32_f16((a), (b), (c), 0, 0, 0)

__device__ __forceinline__ void put_hl(_Float16* ws, int hiBase, int loBase,
                                       int idx, float v) {
  _Float16 hi = (_Float16)v;
  ws[hiBase + idx] = hi;
  ws[loBase + idx] = (_Float16)((v - (float)hi) * 2048.0f);
}

// DPP row_ror:8 == xor-8 within each 16-lane row.
__device__ __forceinline__ float dpp_xor8(float v) {
  int sw = __builtin_amdgcn_update_dpp(0, __float_as_int(v),
                                       0x128 /*row_ror:8*/, 0xF, 0xF, true);
  return __int_as_float(sw);
}

// u-scheme fold (M, A gates). Lane c finishes r=0,1; lane c+8 r=2,3.
__device__ __forceinline__ void fold_u(floatx4 g1, floatx4 g2, bool side,
                                       float out[2]) {
  float u0 = g1[0] + g2[0] * INV2048;
  float u1 = g1[1] + g2[1] * INV2048;
  float u2 = g1[2] + g2[2] * INV2048;
  float u3 = g1[3] + g2[3] * INV2048;
  float t0 = dpp_xor8(g1[0]);
  float t1 = dpp_xor8(g1[1]);
  float t2 = dpp_xor8(u2);
  float t3 = dpp_xor8(u3);
  float base0 = side ? t2 : u0, add0 = side ? g1[2] : t0;
  float base1 = side ? t3 : u1, add1 = side ? g1[3] : t1;
  out[0] = base0 + add0 * INV2048;
  out[1] = base1 + add1 * INV2048;
}

// d gate: spk cols 8-15 exactly 0 -> no cross terms.
__device__ __forceinline__ void fold_d(floatx4 g1, floatx4 g2, bool side,
                                       float out[2]) {
  float u0 = g1[0] + g2[0] * INV2048;
  float u1 = g1[1] + g2[1] * INV2048;
  float u2 = g1[2] + g2[2] * INV2048;
  float u3 = g1[3] + g2[3] * INV2048;
  float t2 = dpp_xor8(u2);
  float t3 = dpp_xor8(u3);
  out[0] = side ? t2 : u0;
  out[1] = side ? t3 : u1;
}

// ---- prep (unchanged from round 7)
__global__ __launch_bounds__(192) void prep(
    const float* __restrict__ W1x, const float* __restrict__ b1x,
    const float* __restrict__ WtauM, const float* __restrict__ btauM,
    const float* __restrict__ WtauAdp, const float* __restrict__ btauAdp,
    _Float16* __restrict__ ws) {
  const int h = blockIdx.x, k = threadIdx.x;
  if (k >= 131) return;
  if (k < 128) {
    float w1 = W1x[h * 130 + 2 + k];
    float s1 = 0.f, s2 = 0.f;
    for (int d = 0; d < 128; ++d) {
      float wd = W1x[d * 130 + 2 + k];
      s1 += WtauM[h * 256 + d] * wd;
      s2 += WtauAdp[h * 256 + d] * wd;
    }
    put_hl(ws, H_M1H, H_M1L, h * 128 + k, w1);
    put_hl(ws, H_MSH, H_MSL, h * 128 + k, s1 * NLOG2E);
    put_hl(ws, H_ASH, H_ASL, h * 128 + k, s2 * NLOG2E);
    put_hl(ws, H_WMH, H_WML, h * 128 + k, WtauM[h * 256 + 128 + k] * NLOG2E);
    put_hl(ws, H_WBH, H_WBL, h * 128 + k, WtauAdp[h * 256 + 128 + k] * NLOG2E);
  } else {
    const int col = k - 128;
    float m1v = (col == 0) ? b1x[h] : W1x[h * 130 + (col - 1)];
    float sm = 0.f, sa = 0.f;
    for (int d = 0; d < 128; ++d) {
      float cv = (col == 0) ? b1x[d] : W1x[d * 130 + (col - 1)];
      sm += WtauM[h * 256 + d] * cv;
      sa += WtauAdp[h * 256 + d] * cv;
    }
    if (col == 0) { sm += btauM[h]; sa += btauAdp[h]; }
    float* EXTF = (float*)ws + F_EXT;
    EXTF[(0 * 3 + col) * 128 + h] = m1v;
    EXTF[(1 * 3 + col) * 128 + h] = sm * NLOG2E;
    EXTF[(2 * 3 + col) * 128 + h] = sa * NLOG2E;
  }
}

// State slabs PER GROUP: two independent recurrences share the block
// barrier and the per-wave weight registers; nothing else.
struct SLds {
  _Float16 spk[2][2][4][256];   // [grp][buf][f][..] packed 8 cols
  _Float16 zero16[8];
  _Float16 mem[2][2][4][512];
  _Float16 bbp[2][2][4][512];
  float red[2][8][8];           // [grp][wg][batch]
  float red2[16];
};

// 512 threads; arch-VGPR cap 128 with weights on the AGPR side (the
// known-good budget). Loop body is liveness-scheduled: each group's
// accumulators are folded to 6 scalars BEFORE the other group's GEMM
// issues, so only ONE group's 48 acc regs are ever live (round-11 fix).
__global__ __launch_bounds__(512, 2) void snn_main(
    const float* __restrict__ x, const float* __restrict__ y,
    const float* __restrict__ h0m, const float* __restrict__ h0s,
    const float* __restrict__ h0b,
    const float* __restrict__ Wlin, const float* __restrict__ blin,
    const _Float16* __restrict__ W, float* __restrict__ wsout) {
  __shared__ SLds L;

  const int tid  = threadIdx.x;
  const int wg   = tid >> 6;      // wave 0..7, owns h-slice [16wg, 16wg+16)
  const int lane = tid & 63;
  const int c    = lane & 15;
  const int q    = lane >> 4;
  const int cc   = c & 7;
  const int bbase = blockIdx.x * MTILE;
  const bool act  = (c < 8);
  const bool side = !act;

  // ---- Register-resident A-frag weights, SHARED by both groups
  half8 m1h[4], m1l[4], msh[4], msl[4], ash[4], asl[4];
  half8 wmh[4], wml[4], wbh[4], wbl[4];
  {
    const int hA = wg * 16 + c;
#pragma unroll
    for (int f = 0; f < 4; ++f) {
      const int o = hA * 128 + f * 32 + q * 8;
      m1h[f] = *(const half8*)&W[H_M1H + o];
      m1l[f] = *(const half8*)&W[H_M1L + o];
      msh[f] = *(const half8*)&W[H_MSH + o];
      msl[f] = *(const half8*)&W[H_MSL + o];
      ash[f] = *(const half8*)&W[H_ASH + o];
      asl[f] = *(const half8*)&W[H_ASL + o];
      wmh[f] = *(const half8*)&W[H_WMH + o];
      wml[f] = *(const half8*)&W[H_WML + o];
      wbh[f] = *(const half8*)&W[H_WBH + o];
      wbl[f] = *(const half8*)&W[H_WBL + o];
    }
  }

  if (tid == 0) {
    *(half8*)&L.zero16[0] = half8{0, 0, 0, 0, 0, 0, 0, 0};
  }

  // ---- f32 ext coefficients (shared by both groups; same h)
  const int h0i = wg * 16 + q * 4 + (side ? 2 : 0);
  const float* CF = (const float*)W + F_EXT;
  floatx2 cd0 = *(const floatx2*)&CF[0 * 128 + h0i];
  floatx2 cd1 = *(const floatx2*)&CF[1 * 128 + h0i];
  floatx2 cd2 = *(const floatx2*)&CF[2 * 128 + h0i];
  floatx2 cm0 = *(const floatx2*)&CF[3 * 128 + h0i];
  floatx2 cm1 = *(const floatx2*)&CF[4 * 128 + h0i];
  floatx2 cm2 = *(const floatx2*)&CF[5 * 128 + h0i];
  floatx2 ca0 = *(const floatx2*)&CF[6 * 128 + h0i];
  floatx2 ca1 = *(const floatx2*)&CF[7 * 128 + h0i];
  floatx2 ca2 = *(const floatx2*)&CF[8 * 128 + h0i];

  // ---- Per-lane state for BOTH groups (2 neurons each)
  float memA[2], spkA[2], bbA[2], memB[2], spkB[2], bbB[2];
  {
    const int giA = (bbase + cc) * HID + h0i;
    const int giB = (bbase + 8 + cc) * HID + h0i;
    float2 t0, t1;
    t0 = *(const float2*)&h0m[giA]; memA[0] = t0.x; memA[1] = t0.y;
    t1 = *(const float2*)&h0m[giB]; memB[0] = t1.x; memB[1] = t1.y;
    t0 = *(const float2*)&h0s[giA]; spkA[0] = t0.x; spkA[1] = t0.y;
    t1 = *(const float2*)&h0s[giB]; spkB[0] = t1.x; spkB[1] = t1.y;
    t0 = *(const float2*)&h0b[giA]; bbA[0] = t0.x; bbA[1] = t0.y;
    t1 = *(const float2*)&h0b[giB]; bbB[0] = t1.x; bbB[1] = t1.y;
  }

  const int fW  = wg >> 1;
  const int qp  = (wg & 1) * 2 + (q >> 1);
  const int jo  = (q & 1) * 4 + (side ? 2 : 0);
  const int wiH = (qp * 16 + cc) * 8 + jo;
  const int wiL = wiH + 64;
  const int wiS = (qp * 8 + cc) * 8 + jo;
  const int ri  = lane * 8;
  const _Float16* spkA0 = act ? &L.spk[0][0][0][(q * 8 + cc) * 8] : L.zero16;
  const _Float16* spkA1 = act ? &L.spk[0][1][0][(q * 8 + cc) * 8] : L.zero16;
  const _Float16* spkB0 = act ? &L.spk[1][0][0][(q * 8 + cc) * 8] : L.zero16;
  const _Float16* spkB1 = act ? &L.spk[1][1][0][(q * 8 + cc) * 8] : L.zero16;
  const int spkStep = act ? 256 : 0;

  {   // initial state into buf 0, both groups
    half2h ps2, mh2, ml2, bh2, bl2;
#pragma unroll
    for (int rr = 0; rr < 2; ++rr) {
      ps2[rr] = (_Float16)spkA[rr];
      float v = memA[rr]; _Float16 hi = (_Float16)v;
      mh2[rr] = hi; ml2[rr] = (_Float16)((v - (float)hi) * 2048.0f);
      v = bbA[rr]; hi = (_Float16)v;
      bh2[rr] = hi; bl2[rr] = (_Float16)((v - (float)hi) * 2048.0f);
    }
    *(half2h*)&L.spk[0][0][fW][wiS] = ps2;
    *(half2h*)&L.mem[0][0][fW][wiH] = mh2; *(half2h*)&L.mem[0][0][fW][wiL] = ml2;
    *(half2h*)&L.bbp[0][0][fW][wiH] = bh2; *(half2h*)&L.bbp[0][0][fW][wiL] = bl2;
#pragma unroll
    for (int rr = 0; rr < 2; ++rr) {
      ps2[rr] = (_Float16)spkB[rr];
      float v = memB[rr]; _Float16 hi = (_Float16)v;
      mh2[rr] = hi; ml2[rr] = (_Float16)((v - (float)hi) * 2048.0f);
      v = bbB[rr]; hi = (_Float16)v;
      bh2[rr] = hi; bl2[rr] = (_Float16)((v - (float)hi) * 2048.0f);
    }
    *(half2h*)&L.spk[1][0][fW][wiS] = ps2;
    *(half2h*)&L.mem[1][0][fW][wiH] = mh2; *(half2h*)&L.mem[1][0][fW][wiL] = ml2;
    *(half2h*)&L.bbp[1][0][fW][wiH] = bh2; *(half2h*)&L.bbp[1][0][fW][wiL] = bl2;
  }
  __syncthreads();

  // x streams for both groups, prefetched one step ahead.
  const float* xbA = x + (size_t)(bbase + cc) * 2;
  const float* xbB = xbA + 16;   // +8 batches
  float2 xvA = *(const float2*)xbA;
  float2 xvB = *(const float2*)xbB;

#pragma unroll 1
  for (int t = 0; t < S_LEN; ++t) {
    const int p = t & 1, pn = p ^ 1;
    const size_t tn = (t + 1 < S_LEN) ? (size_t)(t + 1) : (size_t)t;
    float2 xnA = *(const float2*)(xbA + tn * (size_t)(BATCH * 2));
    float2 xnB = *(const float2*)(xbB + tn * (size_t)(BATCH * 2));

    const _Float16* sBA = p ? spkA1 : spkA0;
    const _Float16* sBB = p ? spkB1 : spkB0;

    // ================= GROUP A GEMM =================
    floatx4 d1 = {0,0,0,0}, d2 = {0,0,0,0}, m1 = {0,0,0,0},
            m2 = {0,0,0,0}, a1 = {0,0,0,0}, a2 = {0,0,0,0};
#pragma unroll
    for (int f = 0; f < 4; ++f) {
      half8 S = *(const half8*)&sBA[f * spkStep];
      half8 M = *(const half8*)&L.mem[0][p][f][ri];
      half8 B = *(const half8*)&L.bbp[0][p][f][ri];
      d1 = MFMA(m1h[f], S, d1);
      d2 = MFMA(m1l[f], S, d2);
      m1 = MFMA(msh[f], S, m1);
      m1 = MFMA(wmh[f], M, m1);
      m2 = MFMA(msl[f], S, m2);
      m2 = MFMA(wml[f], M, m2);
      a1 = MFMA(ash[f], S, a1);
      a1 = MFMA(wbh[f], B, a1);
      a2 = MFMA(asl[f], S, a2);
      a2 = MFMA(wbl[f], B, a2);
    }
    // ---- fold A immediately: 48 acc regs -> 6 scalars + 4 exps in flight
    float preM_A[2], preA_A[2], den_A[2];
    fold_u(m1, m2, side, preM_A);
    float eM0A = __builtin_amdgcn_exp2f(preM_A[0] + cm0[0] + cm1[0] * xvA.x + cm2[0] * xvA.y);
    float eM1A = __builtin_amdgcn_exp2f(preM_A[1] + cm0[1] + cm1[1] * xvA.x + cm2[1] * xvA.y);
    fold_u(a1, a2, side, preA_A);
    float eA0A = __builtin_amdgcn_exp2f(preA_A[0] + ca0[0] + ca1[0] * xvA.x + ca2[0] * xvA.y);
    float eA1A = __builtin_amdgcn_exp2f(preA_A[1] + ca0[1] + ca1[1] * xvA.x + ca2[1] * xvA.y);
    fold_d(d1, d2, side, den_A);
    float tMA[2] = { __builtin_amdgcn_rcpf(1.0f + eM0A),
                     __builtin_amdgcn_rcpf(1.0f + eM1A) };
    float tAA[2] = { __builtin_amdgcn_rcpf(1.0f + eA0A),
                     __builtin_amdgcn_rcpf(1.0f + eA1A) };

    // ================= GROUP B GEMM (A's update hides under it) ========
    d1 = floatx4{0,0,0,0}; d2 = floatx4{0,0,0,0};
    m1 = floatx4{0,0,0,0}; m2 = floatx4{0,0,0,0};
    a1 = floatx4{0,0,0,0}; a2 = floatx4{0,0,0,0};
#pragma unroll
    for (int f = 0; f < 4; ++f) {
      half8 S = *(const half8*)&sBB[f * spkStep];
      half8 M = *(const half8*)&L.mem[1][p][f][ri];
      half8 B = *(const half8*)&L.bbp[1][p][f][ri];
      d1 = MFMA(m1h[f], S, d1);
      d2 = MFMA(m1l[f], S, d2);
      m1 = MFMA(msh[f], S, m1);
      m1 = MFMA(wmh[f], M, m1);
      m2 = MFMA(msl[f], S, m2);
      m2 = MFMA(wml[f], M, m2);
      a1 = MFMA(ash[f], S, a1);
      a1 = MFMA(wbh[f], B, a1);
      a2 = MFMA(asl[f], S, a2);
      a2 = MFMA(wbl[f], B, a2);
    }

    // ---- update + pack + store A (VALU work, overlaps B's MFMA drain)
    {
      half2h ps2, mh2, ml2, bh2, bl2;
#pragma unroll
      for (int rr = 0; rr < 2; ++rr) {
        float dv = den_A[rr] + cd0[rr] + cd1[rr] * xvA.x + cd2[rr] * xvA.y;
        bbA[rr] = tAA[rr] * bbA[rr] + (1.0f - tAA[rr]) * spkA[rr];
        float Bth = 0.01f + 1.8f * bbA[rr];
        memA[rr] = memA[rr] * tMA[rr] + (1.0f - tMA[rr]) * dv - Bth * spkA[rr];
        spkA[rr] = (memA[rr] - Bth) > 0.0f ? 1.0f : 0.0f;
        ps2[rr] = (_Float16)spkA[rr];
        float v = bbA[rr]; _Float16 hi = (_Float16)v;
        bh2[rr] = hi; bl2[rr] = (_Float16)((v - (float)hi) * 2048.0f);
        v = memA[rr]; hi = (_Float16)v;
        mh2[rr] = hi; ml2[rr] = (_Float16)((v - (float)hi) * 2048.0f);
      }
      *(half2h*)&L.bbp[0][pn][fW][wiH] = bh2;
      *(half2h*)&L.bbp[0][pn][fW][wiL] = bl2;
      *(half2h*)&L.spk[0][pn][fW][wiS] = ps2;
      *(half2h*)&L.mem[0][pn][fW][wiH] = mh2;
      *(half2h*)&L.mem[0][pn][fW][wiL] = ml2;
    }

    // ---- fold B
    float preM_B[2], preA_B[2], den_B[2];
    fold_u(m1, m2, side, preM_B);
    float eM0B = __builtin_amdgcn_exp2f(preM_B[0] + cm0[0] + cm1[0] * xvB.x + cm2[0] * xvB.y);
    float eM1B = __builtin_amdgcn_exp2f(preM_B[1] + cm0[1] + cm1[1] * xvB.x + cm2[1] * xvB.y);
    fold_u(a1, a2, side, preA_B);
    float eA0B = __builtin_amdgcn_exp2f(preA_B[0] + ca0[0] + ca1[0] * xvB.x + ca2[0] * xvB.y);
    float eA1B = __builtin_amdgcn_exp2f(preA_B[1] + ca0[1] + ca1[1] * xvB.x + ca2[1] * xvB.y);
    fold_d(d1, d2, side, den_B);
    float tMB[2] = { __builtin_amdgcn_rcpf(1.0f + eM0B),
                     __builtin_amdgcn_rcpf(1.0f + eM1B) };
    float tAB[2] = { __builtin_amdgcn_rcpf(1.0f + eA0B),
                     __builtin_amdgcn_rcpf(1.0f + eA1B) };

    // ---- update + pack + store B
    {
      half2h ps2, mh2, ml2, bh2, bl2;
#pragma unroll
      for (int rr = 0; rr < 2; ++rr) {
        float dv = den_B[rr] + cd0[rr] + cd1[rr] * xvB.x + cd2[rr] * xvB.y;
        bbB[rr] = tAB[rr] * bbB[rr] + (1.0f - tAB[rr]) * spkB[rr];
        float Bth = 0.01f + 1.8f * bbB[rr];
        memB[rr] = memB[rr] * tMB[rr] + (1.0f - tMB[rr]) * dv - Bth * spkB[rr];
        spkB[rr] = (memB[rr] - Bth) > 0.0f ? 1.0f : 0.0f;
        ps2[rr] = (_Float16)spkB[rr];
        float v = bbB[rr]; _Float16 hi = (_Float16)v;
        bh2[rr] = hi; bl2[rr] = (_Float16)((v - (float)hi) * 2048.0f);
        v = memB[rr]; hi = (_Float16)v;
        mh2[rr] = hi; ml2[rr] = (_Float16)((v - (float)hi) * 2048.0f);
      }
      *(half2h*)&L.bbp[1][pn][fW][wiH] = bh2;
      *(half2h*)&L.bbp[1][pn][fW][wiL] = bl2;
      *(half2h*)&L.spk[1][pn][fW][wiS] = ps2;
      *(half2h*)&L.mem[1][pn][fW][wiH] = mh2;
      *(half2h*)&L.mem[1][pn][fW][wiL] = ml2;
    }

    xvA = xnA; xvB = xnB;
    __syncthreads();
  }

  // ---- Readout, both groups
  float pA = memA[0] * Wlin[h0i] + memA[1] * Wlin[h0i + 1];
  float pB = memB[0] * Wlin[h0i] + memB[1] * Wlin[h0i + 1];
  pA += __shfl_xor(pA, 8);  pB += __shfl_xor(pB, 8);
  pA += __shfl_xor(pA, 16); pB += __shfl_xor(pB, 16);
  pA += __shfl_xor(pA, 32); pB += __shfl_xor(pB, 32);
  if (lane < 8) { L.red[0][wg][c] = pA; L.red[1][wg][c] = pB; }
  __syncthreads();
  if (tid < 16) {
    const int g = tid >> 3, b = tid & 7;
    float s = 0.0f;
#pragma unroll
    for (int ww = 0; ww < 8; ++ww) s += L.red[g][ww][b];
    float out = s + blin[0];
    float d = out - y[bbase + g * 8 + b];
    L.red2[tid] = d * d;
  }
  __syncthreads();
  if (tid == 0) {
    float s = 0.0f;
#pragma unroll
    for (int m = 0; m < MTILE; ++m) s += L.red2[m];
    wsout[blockIdx.x] = s;
  }
}

__global__ __launch_bounds__(128) void final_reduce(const float* __restrict__ part,
                                                    float* __restrict__ out) {
  __shared__ float sh[128];
  int t = threadIdx.x;
  sh[t] = part[t];
  __syncthreads();
  for (int s = 64; s > 0; s >>= 1) {
    if (t < s) sh[t] += sh[t + s];
    __syncthreads();
  }
  if (t == 0) out[0] = sh[0] * (1.0f / (float)BATCH);
}

extern "C" void kernel_launch(void* const* d_in, const int* in_sizes, int n_in,
                              void* d_out, int out_size, void* d_ws, size_t ws_size,
                              hipStream_t stream) {
  const float* x       = (const float*)d_in[0];
  const float* y       = (const float*)d_in[1];
  const float* h0m     = (const float*)d_in[2];
  const float* h0s     = (const float*)d_in[3];
  const float* h0b     = (const float*)d_in[4];
  const float* W1x     = (const float*)d_in[5];
  const float* b1x     = (const float*)d_in[6];
  const float* WtauM   = (const float*)d_in[7];
  const float* btauM   = (const float*)d_in[8];
  const float* WtauAdp = (const float*)d_in[9];
  const float* btauAdp = (const float*)d_in[10];
  const float* Wlin    = (const float*)d_in[11];
  const float* blin    = (const float*)d_in[12];
  _Float16* wsf16 = (_Float16*)d_ws;
  float* wspart = (float*)d_ws + OFF_PART_F;

  prep<<<128, 192, 0, stream>>>(W1x, b1x, WtauM, btauM, WtauAdp, btauAdp, wsf16);
  snn_main<<<NBLK, 512, 0, stream>>>(x, y, h0m, h0s, h0b, Wlin, blin,
                                     wsf16, wspart);
  final_reduce<<<1, 128, 0, stream>>>(wspart, (float*)d_out);
}

// Round 13
// 2965.402 us; speedup vs baseline: 4.3359x; 1.0868x over previous
//
#include <hip/hip_runtime.h>
#include <math.h>

#define S_LEN 1024
#define BATCH 2048
#define MTILE 16              // 16 real batch columns per block
#define HID   128
#define NBLK  (BATCH / MTILE)   // 128 blocks, 512 threads (8 waves)
#define INV2048 (1.0f / 2048.0f)
#define NLOG2E (-1.44269504088896341f)   // folded into M/A gate weights

// ws layout (halfs). m1/ms/as are [128][160]: k<128 real weights,
// k=128..132 ext rows (bias,x0,x1 hi | +c0h,c1h in lo rows 131-132),
// k=133..159 zero. wm/wb are [128][128]. M/A paths pre-scaled by -log2e.
#define H_M1H 0
#define H_M1L 20480
#define H_MSH 40960
#define H_MSL 61440
#define H_ASH 81920
#define H_ASL 102400
#define H_WMH 122880
#define H_WML 139264
#define H_WBH 155648
#define H_WBL 172032
#define OFF_PART_F 94208     // float index of per-block partials [128]

typedef _Float16 half8 __attribute__((ext_vector_type(8)));
typedef _Float16 half4 __attribute__((ext_vector_type(4)));
typedef float floatx4 __attribute__((ext_vector_type(4)));

#define MFMA(a, b, c) __builtin_amdgcn_mfma_f32_16x16x32_f16((a), (b), (c), 0, 0, 0)

__device__ __forceinline__ void put_hl(_Float16* ws, int hiBase, int loBase,
                                       int idx, float v) {
  _Float16 hi = (_Float16)v;
  ws[hiBase + idx] = hi;
  ws[loBase + idx] = (_Float16)((v - (float)hi) * 2048.0f);
}

// ---- prep: fold dense->tau coupling + ext rows into f16 hi/lo arrays.
__global__ __launch_bounds__(192) void prep(
    const float* __restrict__ W1x, const float* __restrict__ b1x,
    const float* __restrict__ WtauM, const float* __restrict__ btauM,
    const float* __restrict__ WtauAdp, const float* __restrict__ btauAdp,
    _Float16* __restrict__ ws) {
  const int h = blockIdx.x, k = threadIdx.x;
  if (k >= 160) return;
  if (k < 128) {
    float w1 = W1x[h * 130 + 2 + k];
    float s1 = 0.f, s2 = 0.f;
    for (int d = 0; d < 128; ++d) {
      float wd = W1x[d * 130 + 2 + k];
      s1 += WtauM[h * 256 + d] * wd;
      s2 += WtauAdp[h * 256 + d] * wd;
    }
    put_hl(ws, H_M1H, H_M1L, h * 160 + k, w1);
    put_hl(ws, H_MSH, H_MSL, h * 160 + k, s1 * NLOG2E);
    put_hl(ws, H_ASH, H_ASL, h * 160 + k, s2 * NLOG2E);
    put_hl(ws, H_WMH, H_WML, h * 128 + k, WtauM[h * 256 + 128 + k] * NLOG2E);
    put_hl(ws, H_WBH, H_WBL, h * 128 + k, WtauAdp[h * 256 + 128 + k] * NLOG2E);
  } else if (k < 133) {
    // rows 128..130: (bias, x0, x1) hi/lo. rows 131..132: hi=0, lo=c{0,1}h
    // so that lo-array * E captures the c_hi * x_lo cross terms.
    const int col = (k == 128) ? 0 : ((k == 129 || k == 131) ? 1 : 2);
    float m1v = (col == 0) ? b1x[h] : W1x[h * 130 + (col - 1)];
    float sm = 0.f, sa = 0.f;
    for (int d = 0; d < 128; ++d) {
      float cv = (col == 0) ? b1x[d] : W1x[d * 130 + (col - 1)];
      sm += WtauM[h * 256 + d] * cv;
      sa += WtauAdp[h * 256 + d] * cv;
    }
    if (col == 0) { sm += btauM[h]; sa += btauAdp[h]; }
    sm *= NLOG2E; sa *= NLOG2E;
    const int idx = h * 160 + k;
    if (k < 131) {
      put_hl(ws, H_M1H, H_M1L, idx, m1v);
      put_hl(ws, H_MSH, H_MSL, idx, sm);
      put_hl(ws, H_ASH, H_ASL, idx, sa);
    } else {
      ws[H_M1H + idx] = (_Float16)0.0f; ws[H_M1L + idx] = (_Float16)m1v;
      ws[H_MSH + idx] = (_Float16)0.0f; ws[H_MSL + idx] = (_Float16)sm;
      ws[H_ASH + idx] = (_Float16)0.0f; ws[H_ASL + idx] = (_Float16)sa;
    }
  } else {
    const int idx = h * 160 + k;
    ws[H_M1H + idx] = 0; ws[H_M1L + idx] = 0;
    ws[H_MSH + idx] = 0; ws[H_MSL + idx] = 0;
    ws[H_ASH + idx] = 0; ws[H_ASL + idx] = 0;
  }
}

// State slabs: per chunk f, 32 k-rows x 16 batch cols = 1 KB. Half-index
// (q'*16 + n)*8 + j = B[k=f*32+q'*8+j][batch n], n = 0..15 ALL REAL.
// Separate hi and lo slabs for mem/bbp (lane-local precision scheme, no
// cross-lane folds). spk is exact f16 (no lo slab). Fully overwritten
// every step -> no zero-init.
struct SLds {
  _Float16 spk[2][4][512];
  _Float16 memh[2][4][512];
  _Float16 meml[2][4][512];
  _Float16 bbph[2][4][512];
  _Float16 bbpl[2][4][512];
  float red[8][16];
  float red2[16];
};

// (512,1): arch-VGPR cap 256 (one 512-thread block/CU = 2 waves/SIMD =
// 256 combined regs/wave). The old (512,2) capped arch at 128 and would
// force the 184-reg weight set + 32 acc to spill.
__global__ __launch_bounds__(512, 1) void snn_main(
    const float* __restrict__ x, const float* __restrict__ y,
    const float* __restrict__ h0m, const float* __restrict__ h0s,
    const float* __restrict__ h0b,
    const float* __restrict__ Wlin, const float* __restrict__ blin,
    const _Float16* __restrict__ W, float* __restrict__ wsout) {
  __shared__ SLds L;

  const int tid  = threadIdx.x;
  const int wg   = tid >> 6;      // wave 0..7, owns h-slice [16wg, 16wg+16)
  const int lane = tid & 63;
  const int c    = lane & 15;     // batch column 0..15 (ALL real)
  const int q    = lane >> 4;
  const int bbase = blockIdx.x * MTILE;

  // ---- Register-resident A-frag weights (ext chunk f=4 in the 160-wide)
  half8 m1h[5], m1l[5], msh[5], msl[5], ash[5], asl[5];
  half8 wmh[4], wml[4], wbh[4], wbl[4];
  {
    const int hA = wg * 16 + c;
#pragma unroll
    for (int f = 0; f < 5; ++f) {
      const int o = hA * 160 + f * 32 + q * 8;
      m1h[f] = *(const half8*)&W[H_M1H + o];
      m1l[f] = *(const half8*)&W[H_M1L + o];
      msh[f] = *(const half8*)&W[H_MSH + o];
      msl[f] = *(const half8*)&W[H_MSL + o];
      ash[f] = *(const half8*)&W[H_ASH + o];
      asl[f] = *(const half8*)&W[H_ASL + o];
    }
#pragma unroll
    for (int f = 0; f < 4; ++f) {
      const int o = hA * 128 + f * 32 + q * 8;
      wmh[f] = *(const half8*)&W[H_WMH + o];
      wml[f] = *(const half8*)&W[H_WML + o];
      wbh[f] = *(const half8*)&W[H_WBH + o];
      wbl[f] = *(const half8*)&W[H_WBL + o];
    }
  }

  // ---- Per-lane state: 4 neurons h = wg*16 + q*4 + r, batch bbase+c
  const int h0i = wg * 16 + q * 4;
  float memv[4], spk4[4], bb[4];
  {
    const int gi = (bbase + c) * HID + h0i;
    float4 tm = *(const float4*)&h0m[gi];
    float4 ts = *(const float4*)&h0s[gi];
    float4 tb = *(const float4*)&h0b[gi];
    memv[0] = tm.x; memv[1] = tm.y; memv[2] = tm.z; memv[3] = tm.w;
    spk4[0] = ts.x; spk4[1] = ts.y; spk4[2] = ts.z; spk4[3] = ts.w;
    bb[0]   = tb.x; bb[1]   = tb.y; bb[2]   = tb.z; bb[3]   = tb.w;
  }

  // State h enters GEMM as B[k=h][n=c]: chunk fW = wg>>1,
  // granule qp = (wg&1)*2 + (q>>1), j = (q&1)*4 + r -> half4 write.
  const int fW = wg >> 1;
  const int qp = (wg & 1) * 2 + (q >> 1);
  const int wi = (qp * 16 + c) * 8 + (q & 1) * 4;
  const int ri = lane * 8;       // identity b128 read

  {   // initial state into buf 0
    half4 ps, mh4, ml4, bh4, bl4;
#pragma unroll
    for (int r = 0; r < 4; ++r) {
      ps[r] = (_Float16)spk4[r];
      float v = memv[r]; _Float16 hi = (_Float16)v;
      mh4[r] = hi; ml4[r] = (_Float16)((v - (float)hi) * 2048.0f);
      v = bb[r]; hi = (_Float16)v;
      bh4[r] = hi; bl4[r] = (_Float16)((v - (float)hi) * 2048.0f);
    }
    *(half4*)&L.spk[0][fW][wi]  = ps;
    *(half4*)&L.memh[0][fW][wi] = mh4; *(half4*)&L.meml[0][fW][wi] = ml4;
    *(half4*)&L.bbph[0][fW][wi] = bh4; *(half4*)&L.bbpl[0][fW][wi] = bl4;
  }
  __syncthreads();

  // E operand mask: only q==0 lanes carry the 5 ext rows.
  const float qm = (q == 0) ? 1.0f : 0.0f;
  const _Float16 e0 = (q == 0) ? (_Float16)1.0f : (_Float16)0.0f;

  // x stream for batch bbase+c, prefetched one step ahead.
  const float* xb = x + (size_t)(bbase + c) * 2;
  float2 xv = *(const float2*)xb;

#pragma unroll 1
  for (int t = 0; t < S_LEN; ++t) {
    const int p = t & 1, pn = p ^ 1;
    const size_t tn = (t + 1 < S_LEN) ? (size_t)(t + 1) : (size_t)t;
    float2 xnx = *(const float2*)(xb + tn * (size_t)(BATCH * 2));

    // Build E = {1, x0h, x1h, x0l, x1l, 0,0,0} (zeros for q>0)
    half8 E;
    {
      float xe0 = xv.x * qm, xe1 = xv.y * qm;
      _Float16 xh0 = (_Float16)xe0, xh1 = (_Float16)xe1;
      _Float16 xl0 = (_Float16)((xe0 - (float)xh0) * 2048.0f);
      _Float16 xl1 = (_Float16)((xe1 - (float)xh1) * 2048.0f);
      E = half8{e0, xh0, xh1, xl0, xl1, 0, 0, 0};
    }

    floatx4 d1 = {0,0,0,0}, d2 = {0,0,0,0};
    floatx4 mA1 = {0,0,0,0}, mA2 = {0,0,0,0}, mA3 = {0,0,0,0};
    floatx4 aA1 = {0,0,0,0}, aA2 = {0,0,0,0}, aA3 = {0,0,0,0};

#pragma unroll
    for (int f = 0; f < 4; ++f) {
      half8 S  = *(const half8*)&L.spk[p][f][ri];
      half8 Mh = *(const half8*)&L.memh[p][f][ri];
      half8 Ml = *(const half8*)&L.meml[p][f][ri];
      half8 Bh = *(const half8*)&L.bbph[p][f][ri];
      half8 Bl = *(const half8*)&L.bbpl[p][f][ri];
      d1  = MFMA(m1h[f], S,  d1);
      d2  = MFMA(m1l[f], S,  d2);
      mA1 = MFMA(msh[f], S,  mA1);
      mA1 = MFMA(wmh[f], Mh, mA1);
      mA2 = MFMA(msl[f], S,  mA2);
      mA2 = MFMA(wml[f], Mh, mA2);
      mA3 = MFMA(wmh[f], Ml, mA3);
      aA1 = MFMA(ash[f], S,  aA1);
      aA1 = MFMA(wbh[f], Bh, aA1);
      aA2 = MFMA(asl[f], S,  aA2);
      aA2 = MFMA(wbl[f], Bh, aA2);
      aA3 = MFMA(wbh[f], Bl, aA3);
    }
    {   // ext chunk: bias + x coupling (hi + cross terms via lo arrays)
      d1  = MFMA(m1h[4], E, d1);
      d2  = MFMA(m1l[4], E, d2);
      mA1 = MFMA(msh[4], E, mA1);
      mA2 = MFMA(msl[4], E, mA2);
      aA1 = MFMA(ash[4], E, aA1);
      aA2 = MFMA(asl[4], E, aA2);
    }

    // ---- Elementwise: 4 real neurons per lane, ALL lane-local (no folds)
    half4 ps, mh4, ml4, bh4, bl4;
#pragma unroll
    for (int r = 0; r < 4; ++r) {
      float dv = d1[r] + d2[r] * INV2048;
      float pM = mA1[r] + (mA2[r] + mA3[r]) * INV2048;
      float pA = aA1[r] + (aA2[r] + aA3[r]) * INV2048;
      float tM = __builtin_amdgcn_rcpf(1.0f + __builtin_amdgcn_exp2f(pM));
      float tA = __builtin_amdgcn_rcpf(1.0f + __builtin_amdgcn_exp2f(pA));
      bb[r] = tA * bb[r] + (1.0f - tA) * spk4[r];
      float Bth = 0.01f + 1.8f * bb[r];
      memv[r] = memv[r] * tM + (1.0f - tM) * dv - Bth * spk4[r];
      spk4[r] = (memv[r] - Bth) > 0.0f ? 1.0f : 0.0f;
      ps[r] = (_Float16)spk4[r];
      float v = bb[r]; _Float16 hi = (_Float16)v;
      bh4[r] = hi; bl4[r] = (_Float16)((v - (float)hi) * 2048.0f);
      v = memv[r]; hi = (_Float16)v;
      mh4[r] = hi; ml4[r] = (_Float16)((v - (float)hi) * 2048.0f);
    }
    *(half4*)&L.bbph[pn][fW][wi] = bh4; *(half4*)&L.bbpl[pn][fW][wi] = bl4;
    *(half4*)&L.spk[pn][fW][wi]  = ps;
    *(half4*)&L.memh[pn][fW][wi] = mh4; *(half4*)&L.meml[pn][fW][wi] = ml4;

    xv = xnx;
    __syncthreads();
  }

  // ---- Readout: out[b] = mem[b,:] @ Wlin + blin
  float part = memv[0] * Wlin[h0i] + memv[1] * Wlin[h0i + 1]
             + memv[2] * Wlin[h0i + 2] + memv[3] * Wlin[h0i + 3];
  part += __shfl_xor(part, 16);   // sum over q
  part += __shfl_xor(part, 32);
  if (lane < 16) L.red[wg][c] = part;
  __syncthreads();
  if (tid < 16) {
    float s = 0.0f;
#pragma unroll
    for (int ww = 0; ww < 8; ++ww) s += L.red[ww][tid];
    float out = s + blin[0];
    float d = out - y[bbase + tid];
    L.red2[tid] = d * d;
  }
  __syncthreads();
  if (tid == 0) {
    float s = 0.0f;
#pragma unroll
    for (int m = 0; m < MTILE; ++m) s += L.red2[m];
    wsout[blockIdx.x] = s;
  }
}

__global__ __launch_bounds__(128) void final_reduce(const float* __restrict__ part,
                                                    float* __restrict__ out) {
  __shared__ float sh[128];
  int t = threadIdx.x;
  sh[t] = part[t];
  __syncthreads();
  for (int s = 64; s > 0; s >>= 1) {
    if (t < s) sh[t] += sh[t + s];
    __syncthreads();
  }
  if (t == 0) out[0] = sh[0] * (1.0f / (float)BATCH);
}

extern "C" void kernel_launch(void* const* d_in, const int* in_sizes, int n_in,
                              void* d_out, int out_size, void* d_ws, size_t ws_size,
                              hipStream_t stream) {
  const float* x       = (const float*)d_in[0];
  const float* y       = (const float*)d_in[1];
  const float* h0m     = (const float*)d_in[2];
  const float* h0s     = (const float*)d_in[3];
  const float* h0b     = (const float*)d_in[4];
  const float* W1x     = (const float*)d_in[5];
  const float* b1x     = (const float*)d_in[6];
  const float* WtauM   = (const float*)d_in[7];
  const float* btauM   = (const float*)d_in[8];
  const float* WtauAdp = (const float*)d_in[9];
  const float* btauAdp = (const float*)d_in[10];
  const float* Wlin    = (const float*)d_in[11];
  const float* blin    = (const float*)d_in[12];
  _Float16* wsf16 = (_Float16*)d_ws;
  float* wspart = (float*)d_ws + OFF_PART_F;

  prep<<<128, 192, 0, stream>>>(W1x, b1x, WtauM, btauM, WtauAdp, btauAdp, wsf16);
  snn_main<<<NBLK, 512, 0, stream>>>(x, y, h0m, h0s, h0b, Wlin, blin,
                                     wsf16, wspart);
  final_reduce<<<1, 128, 0, stream>>>(wspart, (float*)d_out);
}

// Round 14
// 1519.914 us; speedup vs baseline: 8.4595x; 1.9510x over previous
//
#include <hip/hip_runtime.h>
#include <math.h>

#define S_LEN 1024
#define BATCH 2048
#define MTILE 8
#define HID   128
#define NBLK  (BATCH / MTILE)   // 256 blocks -> every CU active
#define INV2048 (1.0f / 2048.0f)
#define NLOG2E (-1.44269504088896341f)   // folded into M/A gate weights

// ws layout, offsets in _Float16 elements. Ten [128][128] hi/lo weight
// arrays; M/A-gate weights are pre-scaled by -log2(e) so the sigmoid is
// rcp(1 + exp2(pre)) with a bare v_exp_f32.
#define H_M1H 0
#define H_M1L 16384
#define H_MSH 32768
#define H_MSL 49152
#define H_ASH 65536
#define H_ASL 81920
#define H_WMH 98304      // [128][128] WtauM[:,128:256] hi (scaled)
#define H_WML 114688
#define H_WBH 131072     // [128][128] WtauAdp[:,128:256] hi (scaled)
#define H_WBL 147456
// f32 ext-coefficient table: 9 arrays of [128] floats, gate-major:
// idx (gate*3 + col)*128 + h ; gate 0=d,1=M,2=A ; col 0=bias,1=x0,2=x1.
// M/A rows pre-scaled by -log2(e); d row unscaled.
#define F_EXT      81920     // float index (== 163840 halfs)
#define OFF_PART_F 83072     // float index of per-block partials [256]

typedef _Float16 half8 __attribute__((ext_vector_type(8)));
typedef _Float16 half4 __attribute__((ext_vector_type(4)));
typedef _Float16 half2h __attribute__((ext_vector_type(2)));
typedef float floatx4 __attribute__((ext_vector_type(4)));
typedef float floatx2 __attribute__((ext_vector_type(2)));

#define MFMA(a, b, c) __builtin_amdgcn_mfma_f32_16x16x32_f16((a), (b), (c), 0, 0, 0)

__device__ __forceinline__ void put_hl(_Float16* ws, int hiBase, int loBase,
                                       int idx, float v) {
  _Float16 hi = (_Float16)v;
  ws[hiBase + idx] = hi;
  ws[loBase + idx] = (_Float16)((v - (float)hi) * 2048.0f);
}

// DPP row_ror:8 == xor-8 within each 16-lane row (8 = half the 16-ring).
// VALU pipe instead of the over-subscribed LDS pipe.
__device__ __forceinline__ float dpp_xor8(float v) {
  int sw = __builtin_amdgcn_update_dpp(0, __float_as_int(v),
                                       0x128 /*row_ror:8*/, 0xF, 0xF, true);
  return __int_as_float(sw);
}

// u-scheme fold for gates with a cross term (M, A): pre-combine
// u_r = hi_r + lo_r/2048 on the natural side, then one exchange each way.
// Lane c finishes r=0,1; lane c+8 finishes r=2,3.
__device__ __forceinline__ void fold_u(floatx4 g1, floatx4 g2, bool side,
                                       float out[2]) {
  float u0 = g1[0] + g2[0] * INV2048;
  float u1 = g1[1] + g2[1] * INV2048;
  float u2 = g1[2] + g2[2] * INV2048;
  float u3 = g1[3] + g2[3] * INV2048;
  float t0 = dpp_xor8(g1[0]);   // act receives cross_0
  float t1 = dpp_xor8(g1[1]);
  float t2 = dpp_xor8(u2);      // side receives act's u2
  float t3 = dpp_xor8(u3);
  float base0 = side ? t2 : u0, add0 = side ? g1[2] : t0;
  float base1 = side ? t3 : u1, add1 = side ? g1[3] : t1;
  out[0] = base0 + add0 * INV2048;
  out[1] = base1 + add1 * INV2048;
}

// d gate: spk cols 8-15 are exactly 0 -> cross terms vanish on both sides.
__device__ __forceinline__ void fold_d(floatx4 g1, floatx4 g2, bool side,
                                       float out[2]) {
  float u0 = g1[0] + g2[0] * INV2048;
  float u1 = g1[1] + g2[1] * INV2048;
  float u2 = g1[2] + g2[2] * INV2048;
  float u3 = g1[3] + g2[3] * INV2048;
  float t2 = dpp_xor8(u2);
  float t3 = dpp_xor8(u3);
  out[0] = side ? t2 : u0;
  out[1] = side ? t3 : u1;
}

// ---- prep: fold dense->tau coupling into f16 hi/lo fragment arrays, plus
// the f32 ext-coefficient table. M/A-gate paths pre-scaled by -log2(e).
__global__ __launch_bounds__(192) void prep(
    const float* __restrict__ W1x, const float* __restrict__ b1x,
    const float* __restrict__ WtauM, const float* __restrict__ btauM,
    const float* __restrict__ WtauAdp, const float* __restrict__ btauAdp,
    _Float16* __restrict__ ws) {
  const int h = blockIdx.x, k = threadIdx.x;
  if (k >= 131) return;
  if (k < 128) {
    float w1 = W1x[h * 130 + 2 + k];
    float s1 = 0.f, s2 = 0.f;
    for (int d = 0; d < 128; ++d) {
      float wd = W1x[d * 130 + 2 + k];
      s1 += WtauM[h * 256 + d] * wd;
      s2 += WtauAdp[h * 256 + d] * wd;
    }
    put_hl(ws, H_M1H, H_M1L, h * 128 + k, w1);
    put_hl(ws, H_MSH, H_MSL, h * 128 + k, s1 * NLOG2E);
    put_hl(ws, H_ASH, H_ASL, h * 128 + k, s2 * NLOG2E);
    put_hl(ws, H_WMH, H_WML, h * 128 + k, WtauM[h * 256 + 128 + k] * NLOG2E);
    put_hl(ws, H_WBH, H_WBL, h * 128 + k, WtauAdp[h * 256 + 128 + k] * NLOG2E);
  } else {
    const int col = k - 128;   // 0: bias, 1: x0-coef, 2: x1-coef
    float m1v = (col == 0) ? b1x[h] : W1x[h * 130 + (col - 1)];
    float sm = 0.f, sa = 0.f;
    for (int d = 0; d < 128; ++d) {
      float cv = (col == 0) ? b1x[d] : W1x[d * 130 + (col - 1)];
      sm += WtauM[h * 256 + d] * cv;
      sa += WtauAdp[h * 256 + d] * cv;
    }
    if (col == 0) { sm += btauM[h]; sa += btauAdp[h]; }
    float* EXTF = (float*)ws + F_EXT;
    EXTF[(0 * 3 + col) * 128 + h] = m1v;
    EXTF[(1 * 3 + col) * 128 + h] = sm * NLOG2E;
    EXTF[(2 * 3 + col) * 128 + h] = sa * NLOG2E;
  }
}

// State slabs. mem/bbp per k-chunk: 1 KB, half-index (q'*16+n')*8+j holds
// B[k=f*32+q'*8+j][n']; n'=0..7 hi, n'=8..15 lo(x2048). spk is PACKED to the
// 8 real cols (spike is exact in f16, no lo) -> 512 B/chunk, fully
// overwritten every step. Side lanes broadcast-read zero16 for S.
struct SLds {
  _Float16 spk[2][4][256];
  _Float16 zero16[8];           // 16 B of zeros, same-address broadcast read
  _Float16 mem[2][4][512];
  _Float16 bbp[2][4][512];
  float red[8][8];
  float red2[8];
};

__global__ __launch_bounds__(512, 2) void snn_main(
    const float* __restrict__ x, const float* __restrict__ y,
    const float* __restrict__ h0m, const float* __restrict__ h0s,
    const float* __restrict__ h0b,
    const float* __restrict__ Wlin, const float* __restrict__ blin,
    const _Float16* __restrict__ W, float* __restrict__ wsout) {
  __shared__ SLds L;

  const int tid  = threadIdx.x;
  const int w    = tid >> 6;      // wave 0..7, owns h-slice [16w, 16w+16)
  const int lane = tid & 63;
  const int c    = lane & 15;     // A-frag m / B-frag n / C col
  const int q    = lane >> 4;
  const int cc   = c & 7;         // batch column within the tile
  const int bbase = blockIdx.x * MTILE;
  const bool act  = (c < 8);
  const bool side = !act;         // side lanes own neurons r=2,3

  // ---- Register-resident A-frag weights (MFMA-only -> AGPR side)
  half8 m1h[4], m1l[4], msh[4], msl[4], ash[4], asl[4];
  half8 wmh[4], wml[4], wbh[4], wbl[4];
  {
    const int hA = w * 16 + c;
#pragma unroll
    for (int f = 0; f < 4; ++f) {
      const int o = hA * 128 + f * 32 + q * 8;
      m1h[f] = *(const half8*)&W[H_M1H + o];
      m1l[f] = *(const half8*)&W[H_M1L + o];
      msh[f] = *(const half8*)&W[H_MSH + o];
      msl[f] = *(const half8*)&W[H_MSL + o];
      ash[f] = *(const half8*)&W[H_ASH + o];
      asl[f] = *(const half8*)&W[H_ASL + o];
      wmh[f] = *(const half8*)&W[H_WMH + o];
      wml[f] = *(const half8*)&W[H_WML + o];
      wbh[f] = *(const half8*)&W[H_WBH + o];
      wbl[f] = *(const half8*)&W[H_WBL + o];
    }
  }

  if (tid == 0) {   // 16 B zero block for c>=8 broadcast S reads
    *(half8*)&L.zero16[0] = half8{0, 0, 0, 0, 0, 0, 0, 0};
  }

  // ---- f32 ext coefficients for this lane's 2 neurons (h0i, h0i+1)
  const int h0i = w * 16 + q * 4 + (side ? 2 : 0);
  const float* CF = (const float*)W + F_EXT;
  floatx2 cd0 = *(const floatx2*)&CF[0 * 128 + h0i];
  floatx2 cd1 = *(const floatx2*)&CF[1 * 128 + h0i];
  floatx2 cd2 = *(const floatx2*)&CF[2 * 128 + h0i];
  floatx2 cm0 = *(const floatx2*)&CF[3 * 128 + h0i];
  floatx2 cm1 = *(const floatx2*)&CF[4 * 128 + h0i];
  floatx2 cm2 = *(const floatx2*)&CF[5 * 128 + h0i];
  floatx2 ca0 = *(const floatx2*)&CF[6 * 128 + h0i];
  floatx2 ca1 = *(const floatx2*)&CF[7 * 128 + h0i];
  floatx2 ca2 = *(const floatx2*)&CF[8 * 128 + h0i];

  // ---- Per-lane recurrent state: EVERY lane owns 2 neurons.
  float memv[2], spk[2], bb[2];
  {
    const int gi = (bbase + cc) * HID + h0i;
    float2 tm = *(const float2*)&h0m[gi];
    float2 ts = *(const float2*)&h0s[gi];
    float2 tb = *(const float2*)&h0b[gi];
    memv[0] = tm.x; memv[1] = tm.y;
    spk[0]  = ts.x; spk[1]  = ts.y;
    bb[0]   = tb.x; bb[1]   = tb.y;
  }

  // State value (h = w*16+q*4+side*2+rr) enters GEMM2 as B[k=h][n]:
  // chunk fW = w>>1, granule qp = (w&1)*2 + (q>>1), j = (q&1)*4 + side*2 + rr.
  const int fW  = w >> 1;
  const int qp  = (w & 1) * 2 + (q >> 1);
  const int jo  = (q & 1) * 4 + (side ? 2 : 0);
  const int wiH = (qp * 16 + cc) * 8 + jo;        // mem/bbp hi (n'=cc)
  const int wiL = wiH + 64;                       // mem/bbp lo (n'=cc+8)
  const int wiS = (qp * 8 + cc) * 8 + jo;         // packed spk
  const int ri  = lane * 8;                       // mem/bbp read (identity)
  const _Float16* spkB0 = act ? &L.spk[0][0][(q * 8 + cc) * 8] : L.zero16;
  const _Float16* spkB1 = act ? &L.spk[1][0][(q * 8 + cc) * 8] : L.zero16;
  const int spkStep = act ? 256 : 0;

  {   // initial state into buf 0 (all lanes, 2 values each)
    half2h ps2, mh2, ml2, bh2, bl2;
#pragma unroll
    for (int rr = 0; rr < 2; ++rr) {
      ps2[rr] = (_Float16)spk[rr];
      float v = memv[rr]; _Float16 hi = (_Float16)v;
      mh2[rr] = hi; ml2[rr] = (_Float16)((v - (float)hi) * 2048.0f);
      v = bb[rr]; hi = (_Float16)v;
      bh2[rr] = hi; bl2[rr] = (_Float16)((v - (float)hi) * 2048.0f);
    }
    *(half2h*)&L.spk[0][fW][wiS] = ps2;
    *(half2h*)&L.mem[0][fW][wiH] = mh2; *(half2h*)&L.mem[0][fW][wiL] = ml2;
    *(half2h*)&L.bbp[0][fW][wiH] = bh2; *(half2h*)&L.bbp[0][fW][wiL] = bl2;
  }
  __syncthreads();

  // Per-lane x stream for batch bbase+cc, prefetched one step ahead.
  const float* xb = x + (size_t)(bbase + cc) * 2;
  float2 xv = *(const float2*)xb;   // x at t=0

#pragma unroll 1
  for (int t = 0; t < S_LEN; ++t) {
    const int p = t & 1, pn = p ^ 1;
    const size_t tn = (t + 1 < S_LEN) ? (size_t)(t + 1) : (size_t)t;
    float2 xnx = *(const float2*)(xb + tn * (size_t)(BATCH * 2));  // prefetch

    const _Float16* sB = p ? spkB1 : spkB0;

    floatx4 d1 = {0.f,0.f,0.f,0.f}, d2 = {0.f,0.f,0.f,0.f};
    floatx4 m1 = {0.f,0.f,0.f,0.f}, m2 = {0.f,0.f,0.f,0.f};
    floatx4 a1 = {0.f,0.f,0.f,0.f}, a2 = {0.f,0.f,0.f,0.f};

#pragma unroll
    for (int f = 0; f < 4; ++f) {
      half8 S = *(const half8*)&sB[f * spkStep];   // [spk] (0 for c>=8)
      half8 M = *(const half8*)&L.mem[p][f][ri];   // [mh  | ml]
      half8 B = *(const half8*)&L.bbp[p][f][ri];   // [bh  | bl]
      d1 = MFMA(m1h[f], S, d1);
      d2 = MFMA(m1l[f], S, d2);
      m1 = MFMA(msh[f], S, m1);
      m1 = MFMA(wmh[f], M, m1);    // cols0-7: wmh*mh ; cols8-15: wmh*ml
      m2 = MFMA(msl[f], S, m2);
      m2 = MFMA(wml[f], M, m2);    // cols0-7: wml*mh ; cols8-15: junk
      a1 = MFMA(ash[f], S, a1);
      a1 = MFMA(wbh[f], B, a1);
      a2 = MFMA(asl[f], S, a2);
      a2 = MFMA(wbl[f], B, a2);
    }

    const float xc0 = xv.x, xc1 = xv.y;

    // M gate first: its exp2 issues while the a/d folds run on the VALU.
    float preM[2], preA[2], den[2];
    fold_u(m1, m2, side, preM);
    float pM0 = preM[0] + cm0[0] + cm1[0] * xc0 + cm2[0] * xc1;
    float pM1 = preM[1] + cm0[1] + cm1[1] * xc0 + cm2[1] * xc1;
    float eM0 = __builtin_amdgcn_exp2f(pM0);   // weights pre-scaled by -log2e
    float eM1 = __builtin_amdgcn_exp2f(pM1);
    fold_u(a1, a2, side, preA);
    float pA0 = preA[0] + ca0[0] + ca1[0] * xc0 + ca2[0] * xc1;
    float pA1 = preA[1] + ca0[1] + ca1[1] * xc0 + ca2[1] * xc1;
    float eA0 = __builtin_amdgcn_exp2f(pA0);
    float eA1 = __builtin_amdgcn_exp2f(pA1);
    fold_d(d1, d2, side, den);

    float tM[2] = { __builtin_amdgcn_rcpf(1.0f + eM0),
                    __builtin_amdgcn_rcpf(1.0f + eM1) };
    float tA[2] = { __builtin_amdgcn_rcpf(1.0f + eA0),
                    __builtin_amdgcn_rcpf(1.0f + eA1) };

    // ---- Elementwise update: 2 real neurons per lane (64 lanes busy).
    half2h ps2, mh2, ml2, bh2, bl2;
#pragma unroll
    for (int rr = 0; rr < 2; ++rr) {
      float dv = den[rr] + cd0[rr] + cd1[rr] * xc0 + cd2[rr] * xc1;
      bb[rr] = tA[rr] * bb[rr] + (1.0f - tA[rr]) * spk[rr];
      float Bth = 0.01f + 1.8f * bb[rr];
      memv[rr] = memv[rr] * tM[rr] + (1.0f - tM[rr]) * dv - Bth * spk[rr];
      spk[rr] = (memv[rr] - Bth) > 0.0f ? 1.0f : 0.0f;
      ps2[rr] = (_Float16)spk[rr];
      float v = bb[rr]; _Float16 hi = (_Float16)v;
      bh2[rr] = hi; bl2[rr] = (_Float16)((v - (float)hi) * 2048.0f);
      v = memv[rr]; hi = (_Float16)v;
      mh2[rr] = hi; ml2[rr] = (_Float16)((v - (float)hi) * 2048.0f);
    }
    // bbp/spk stores first: start the lgkm drain while mem pack retires.
    *(half2h*)&L.bbp[pn][fW][wiH] = bh2; *(half2h*)&L.bbp[pn][fW][wiL] = bl2;
    *(half2h*)&L.spk[pn][fW][wiS] = ps2;
    *(half2h*)&L.mem[pn][fW][wiH] = mh2; *(half2h*)&L.mem[pn][fW][wiL] = ml2;

    xv = xnx;
    __syncthreads();
  }

  // ---- Readout: out[b] = mem[b,:] @ Wlin + blin; per-block loss partial
  float part = memv[0] * Wlin[h0i] + memv[1] * Wlin[h0i + 1];
  part += __shfl_xor(part, 8);    // sum over side
  part += __shfl_xor(part, 16);   // sum over q
  part += __shfl_xor(part, 32);
  if (lane < 8) L.red[w][c] = part;
  __syncthreads();
  if (tid < 8) {
    float s = 0.0f;
#pragma unroll
    for (int ww = 0; ww < 8; ++ww) s += L.red[ww][tid];
    float out = s + blin[0];
    float d = out - y[bbase + tid];
    L.red2[tid] = d * d;
  }
  __syncthreads();
  if (tid == 0) {
    float s = 0.0f;
#pragma unroll
    for (int m = 0; m < MTILE; ++m) s += L.red2[m];
    wsout[blockIdx.x] = s;
  }
}

__global__ __launch_bounds__(256) void final_reduce(const float* __restrict__ part,
                                                    float* __restrict__ out) {
  __shared__ float sh[256];
  int t = threadIdx.x;
  sh[t] = part[t];
  __syncthreads();
  for (int s = 128; s > 0; s >>= 1) {
    if (t < s) sh[t] += sh[t + s];
    __syncthreads();
  }
  if (t == 0) out[0] = sh[0] * (1.0f / (float)BATCH);
}

extern "C" void kernel_launch(void* const* d_in, const int* in_sizes, int n_in,
                              void* d_out, int out_size, void* d_ws, size_t ws_size,
                              hipStream_t stream) {
  const float* x       = (const float*)d_in[0];
  const float* y       = (const float*)d_in[1];
  const float* h0m     = (const float*)d_in[2];
  const float* h0s     = (const float*)d_in[3];
  const float* h0b     = (const float*)d_in[4];
  const float* W1x     = (const float*)d_in[5];
  const float* b1x     = (const float*)d_in[6];
  const float* WtauM   = (const float*)d_in[7];
  const float* btauM   = (const float*)d_in[8];
  const float* WtauAdp = (const float*)d_in[9];
  const float* btauAdp = (const float*)d_in[10];
  const float* Wlin    = (const float*)d_in[11];
  const float* blin    = (const float*)d_in[12];
  _Float16* wsf16 = (_Float16*)d_ws;
  float* wspart = (float*)d_ws + OFF_PART_F;

  prep<<<128, 192, 0, stream>>>(W1x, b1x, WtauM, btauM, WtauAdp, btauAdp, wsf16);
  snn_main<<<NBLK, 512, 0, stream>>>(x, y, h0m, h0s, h0b, Wlin, blin,
                                     wsf16, wspart);
  final_reduce<<<1, 256, 0, stream>>>(wspart, (float*)d_out);
}